// Round 7
// baseline (1055.830 us; speedup 1.0000x reference)
//
#include <hip/hip_runtime.h>
#include <hip/hip_bf16.h>
#include <math.h>

#define HH 128
#define FF 128
#define GG 50
#define NLAYERS 6

typedef __attribute__((ext_vector_type(8))) short bf16x8;
typedef __attribute__((ext_vector_type(4))) float f32x4;

static __device__ __forceinline__ float ssp(float x) {
    return fmaxf(x, 0.f) + __logf(1.f + __expf(-fabsf(x))) - 0.6931471805599453f;
}

static __device__ __forceinline__ short f2bf(float x) {
    union { float f; unsigned u; } c; c.f = x;
    unsigned r = (c.u + 0x7FFF + ((c.u >> 16) & 1)) >> 16;
    return (short)r;
}

static __device__ __forceinline__ float bf2f(unsigned short x) {
    union { unsigned u; float f; } c; c.u = ((unsigned)x) << 16; return c.f;
}
static __device__ __forceinline__ float bf2f_lo(unsigned p) {
    union { unsigned u; float f; } c; c.u = p << 16; return c.f;
}
static __device__ __forceinline__ float bf2f_hi(unsigned p) {
    union { unsigned u; float f; } c; c.u = p & 0xFFFF0000u; return c.f;
}

// ---------------- sort pipeline: hist -> scan -> scatter ----------------
__global__ void hist_kernel(const int* __restrict__ col, int* __restrict__ counts, int E_) {
    int e = blockIdx.x * 256 + threadIdx.x;
    if (e < E_) atomicAdd(&counts[col[e]], 1);
}

// writes exclusive prefix into BOTH offsets (kept) and woff (mutated by scatter)
__global__ __launch_bounds__(1024) void scan_kernel(const int* __restrict__ counts,
                                                    int* __restrict__ offsets,
                                                    int* __restrict__ woff, int N_) {
    __shared__ int wsum[16];
    __shared__ int carry_s;
    const int tid = threadIdx.x;
    const int lane = tid & 63, wid = tid >> 6;
    if (tid == 0) carry_s = 0;
    __syncthreads();
    for (int base = 0; base < N_; base += 1024) {
        int i = base + tid;
        int val = (i < N_) ? counts[i] : 0;
        int x = val;
#pragma unroll
        for (int d = 1; d < 64; d <<= 1) {
            int t = __shfl_up(x, d, 64);
            if (lane >= d) x += t;
        }
        if (lane == 63) wsum[wid] = x;
        int carry = carry_s;
        __syncthreads();
        if (wid == 0) {
            int s = (lane < 16) ? wsum[lane] : 0;
#pragma unroll
            for (int d = 1; d < 16; d <<= 1) {
                int t = __shfl_up(s, d, 64);
                if (lane >= d) s += t;
            }
            if (lane < 16) wsum[lane] = s;
            if (lane == 15) carry_s = carry + s;
        }
        __syncthreads();
        int woffset = (wid > 0) ? wsum[wid - 1] : 0;
        if (i < N_) {
            int ex = carry + woffset + x - val;  // exclusive
            offsets[i] = ex;
            woff[i] = ex;
        }
        __syncthreads();
    }
}

__global__ void scatter_kernel(const float* __restrict__ pos,
                               const float* __restrict__ offs,
                               const int* __restrict__ row,
                               const int* __restrict__ col,
                               int* __restrict__ woff,
                               int* __restrict__ srow,
                               float* __restrict__ sdist, float* __restrict__ sCb,
                               int E_) {
    int e = blockIdx.x * 256 + threadIdx.x;
    if (e >= E_) return;
    int r = row[e], c = col[e];
    float dx = pos[c * 3 + 0] + offs[e * 3 + 0] - pos[r * 3 + 0];
    float dy = pos[c * 3 + 1] + offs[e * 3 + 1] - pos[r * 3 + 1];
    float dz = pos[c * 3 + 2] + offs[e * 3 + 2] - pos[r * 3 + 2];
    float d = sqrtf(dx * dx + dy * dy + dz * dz);
    int p = atomicAdd(&woff[c], 1);
    srow[p] = r;
    sdist[p] = d;
    sCb[p] = 0.5f * (cosf(d * 0.6283185307179586f) + 1.0f);
}

// ------------- prep: transpose + bf16 all weights (all layers) -------------
__global__ __launch_bounds__(256) void prep_kernel(
    const float* __restrict__ w1, const float* __restrict__ w2,
    const float* __restrict__ u1, const float* __restrict__ u2,
    const float* __restrict__ lin_w,
    short* __restrict__ w1t, short* __restrict__ w2t,
    short* __restrict__ u1t, short* __restrict__ u2t, short* __restrict__ lin_wt) {
    int idx = blockIdx.x * 256 + threadIdx.x;
    if (idx < NLAYERS * FF * FF) {
        int l = idx >> 14, r = idx & 16383, a = r >> 7, b = r & 127;
        size_t src = (size_t)l * FF * FF + (size_t)b * FF + a;  // [l][b][a]
        w2t[idx] = f2bf(w2[src]);
        u1t[idx] = f2bf(u1[src]);
        u2t[idx] = f2bf(u2[src]);
        lin_wt[idx] = f2bf(lin_w[src]);
    }
    if (idx < NLAYERS * FF * 64) {
        int l = idx >> 13, r = idx & 8191, fo = r >> 6, g = r & 63;
        w1t[idx] = f2bf(g < GG ? w1[((size_t)l * GG + g) * FF + fo] : 0.f);
    }
}

// ---------------- vproj0 = v(f32) @ lin_w[0]  via MFMA, bf16 out ----------------
__global__ __launch_bounds__(256) void vproj0_kernel(const float* __restrict__ vb,
                                                     const short* __restrict__ lwt,
                                                     unsigned short* __restrict__ out,
                                                     int N_) {
    const int tid = threadIdx.x;
    const int lane = tid & 63, wave = tid >> 6;
    const int l15 = lane & 15, l4 = lane >> 4;
    const int n0 = wave * 32;
    const int nb0 = blockIdx.x * 64;
    bf16x8 bw[2][4];
#pragma unroll
    for (int n = 0; n < 2; n++)
#pragma unroll
        for (int ks = 0; ks < 4; ks++)
            bw[n][ks] = *(const bf16x8*)&lwt[(n0 + n * 16 + l15) * 128 + ks * 32 + l4 * 8];
#pragma unroll
    for (int m = 0; m < 4; m++) {
        f32x4 acc0 = {0.f, 0.f, 0.f, 0.f}, acc1 = {0.f, 0.f, 0.f, 0.f};
        int arow = nb0 + m * 16 + l15;
        const float* ap = &vb[(size_t)(arow < N_ ? arow : 0) * HH];
#pragma unroll
        for (int ks = 0; ks < 4; ks++) {
            float4 x0 = *(const float4*)&ap[ks * 32 + l4 * 8];
            float4 x1 = *(const float4*)&ap[ks * 32 + l4 * 8 + 4];
            bf16x8 a = {f2bf(x0.x), f2bf(x0.y), f2bf(x0.z), f2bf(x0.w),
                        f2bf(x1.x), f2bf(x1.y), f2bf(x1.z), f2bf(x1.w)};
            acc0 = __builtin_amdgcn_mfma_f32_16x16x32_bf16(a, bw[0][ks], acc0, 0, 0, 0);
            acc1 = __builtin_amdgcn_mfma_f32_16x16x32_bf16(a, bw[1][ks], acc1, 0, 0, 0);
        }
#pragma unroll
        for (int r = 0; r < 4; r++) {
            int gn = nb0 + m * 16 + l4 * 4 + r;
            if (gn < N_) {
                out[(size_t)gn * FF + n0 + l15] = (unsigned short)f2bf(acc0[r]);
                out[(size_t)gn * FF + n0 + 16 + l15] = (unsigned short)f2bf(acc1[r]);
            }
        }
    }
}

// ---------------- fused edge kernel: MFMA filter + msg materialization ----------------
// LDS = h1 only (17.4 KB) -> 8 blocks/CU. No atomics; msg stores coalesced.
__global__ __launch_bounds__(256, 8) void edge_mfma_kernel(
    const float* __restrict__ sdist, const float* __restrict__ sCb,
    const unsigned short* __restrict__ vproj, const int* __restrict__ srow,
    const short* __restrict__ w1t, const float* __restrict__ b1,
    const short* __restrict__ w2t, const float* __restrict__ b2,
    unsigned short* __restrict__ msg, int E_) {
    __shared__ __align__(16) short h1_s[64 * 136];
    const int tid = threadIdx.x;
    const int lane = tid & 63, wave = tid >> 6;
    const int l15 = lane & 15, l4 = lane >> 4;
    const int n0 = wave * 32;
    const int e0 = blockIdx.x * 64;

    bf16x8 bw1[2][2], bw2[2][4];
    float bias1[2], bias2[2];
#pragma unroll
    for (int n = 0; n < 2; n++) {
        const int fo = n0 + n * 16 + l15;
        bias1[n] = b1[fo];
        bias2[n] = b2[fo];
#pragma unroll
        for (int ks = 0; ks < 2; ks++)
            bw1[n][ks] = *(const bf16x8*)&w1t[fo * 64 + ks * 32 + l4 * 8];
#pragma unroll
        for (int ks = 0; ks < 4; ks++)
            bw2[n][ks] = *(const bf16x8*)&w2t[fo * 128 + ks * 32 + l4 * 8];
    }

    // GEMM1: h1 = ssp(demb @ w1 + b1), demb computed in registers
    const float STEP = 5.0f / 49.0f;
    const float COEFF = -0.5f / (STEP * STEP);
#pragma unroll
    for (int m = 0; m < 4; m++) {
        int ge = e0 + m * 16 + l15;
        float d = sdist[ge < E_ ? ge : 0];
        bf16x8 a0, a1;
#pragma unroll
        for (int j = 0; j < 8; j++) {
            int g0 = l4 * 8 + j;                       // 0..31
            float x0 = fmaf((float)g0, -STEP, d);
            a0[j] = f2bf(__expf(COEFF * x0 * x0));
            int g1 = 32 + l4 * 8 + j;                  // 32..63
            float x1 = fmaf((float)g1, -STEP, d);
            a1[j] = (g1 < GG) ? f2bf(__expf(COEFF * x1 * x1)) : (short)0;
        }
#pragma unroll
        for (int n = 0; n < 2; n++) {
            f32x4 acc = {bias1[n], bias1[n], bias1[n], bias1[n]};
            acc = __builtin_amdgcn_mfma_f32_16x16x32_bf16(a0, bw1[n][0], acc, 0, 0, 0);
            acc = __builtin_amdgcn_mfma_f32_16x16x32_bf16(a1, bw1[n][1], acc, 0, 0, 0);
            const int f = n0 + n * 16 + l15;
#pragma unroll
            for (int r = 0; r < 4; r++)
                h1_s[(m * 16 + l4 * 4 + r) * 136 + f] = f2bf(ssp(acc[r]));
        }
    }
    __syncthreads();

    // GEMM2 into registers, then msg = Wf * C * vproj[srow]  (bf16, coalesced)
#pragma unroll
    for (int m = 0; m < 4; m++) {
        f32x4 accA = {bias2[0], bias2[0], bias2[0], bias2[0]};
        f32x4 accB = {bias2[1], bias2[1], bias2[1], bias2[1]};
#pragma unroll
        for (int ks = 0; ks < 4; ks++) {
            bf16x8 a = *(const bf16x8*)&h1_s[(m * 16 + l15) * 136 + ks * 32 + l4 * 8];
            accA = __builtin_amdgcn_mfma_f32_16x16x32_bf16(a, bw2[0][ks], accA, 0, 0, 0);
            accB = __builtin_amdgcn_mfma_f32_16x16x32_bf16(a, bw2[1][ks], accB, 0, 0, 0);
        }
#pragma unroll
        for (int r = 0; r < 4; r++) {
            int ge = e0 + m * 16 + l4 * 4 + r;
            if (ge < E_) {
                float cb = sCb[ge];
                const unsigned short* vp = &vproj[(size_t)srow[ge] * FF];
                float p0 = accA[r] * cb * bf2f(vp[n0 + l15]);
                float p1 = accB[r] * cb * bf2f(vp[n0 + 16 + l15]);
                msg[(size_t)ge * FF + n0 + l15] = (unsigned short)f2bf(p0);
                msg[(size_t)ge * FF + n0 + 16 + l15] = (unsigned short)f2bf(p1);
            }
        }
    }
}

// ------- node kernel: CSR segment-sum of msg -> LDS agg; MLP; vproj_next -------
__global__ __launch_bounds__(256) void node_mfma_kernel(
    const unsigned short* __restrict__ msg, const int* __restrict__ off_start,
    const int* __restrict__ off_end, const short* __restrict__ u1t,
    const float* __restrict__ ub1, const short* __restrict__ u2t,
    const float* __restrict__ ub2, float* __restrict__ vb,
    const short* __restrict__ lwt_next, unsigned short* __restrict__ vproj, int N_) {
    __shared__ __align__(16) float agg_s[32][132];
    __shared__ __align__(16) short t1_s[32 * 136];
    __shared__ __align__(16) short t2_s[32 * 136];
    const int tid = threadIdx.x;
    const int lane = tid & 63, wave = tid >> 6;
    const int l15 = lane & 15, l4 = lane >> 4;
    const int n0 = wave * 32;
    const int nb0 = blockIdx.x * 32;

    // ---- CSR aggregation: wave w sums nodes nb0 + w*8 .. +8 (deterministic order)
    {
        const int t = lane;   // feature pair index: features 2t, 2t+1
        for (int s = 0; s < 8; s++) {
            int nl = wave * 8 + s;
            int n = nb0 + nl;
            float a0 = 0.f, a1 = 0.f;
            if (n < N_) {
                int e = off_start[n];
                const int eend = off_end[n];
                for (; e + 1 < eend; e += 2) {
                    unsigned p0 = *(const unsigned*)&msg[(size_t)e * FF + 2 * t];
                    unsigned p1 = *(const unsigned*)&msg[(size_t)(e + 1) * FF + 2 * t];
                    a0 += bf2f_lo(p0) + bf2f_lo(p1);
                    a1 += bf2f_hi(p0) + bf2f_hi(p1);
                }
                if (e < eend) {
                    unsigned p0 = *(const unsigned*)&msg[(size_t)e * FF + 2 * t];
                    a0 += bf2f_lo(p0);
                    a1 += bf2f_hi(p0);
                }
            }
            agg_s[nl][2 * t] = a0;
            agg_s[nl][2 * t + 1] = a1;
        }
    }
    __syncthreads();

    // GEMM1: t1 = ssp(agg @ u1 + ub1)
    {
        bf16x8 bw[2][4];
        float bias[2];
#pragma unroll
        for (int n = 0; n < 2; n++) {
            bias[n] = ub1[n0 + n * 16 + l15];
#pragma unroll
            for (int ks = 0; ks < 4; ks++)
                bw[n][ks] = *(const bf16x8*)&u1t[(n0 + n * 16 + l15) * 128 + ks * 32 + l4 * 8];
        }
#pragma unroll
        for (int m = 0; m < 2; m++) {
            const float* ap = &agg_s[m * 16 + l15][0];
            f32x4 acc0 = {bias[0], bias[0], bias[0], bias[0]};
            f32x4 acc1 = {bias[1], bias[1], bias[1], bias[1]};
#pragma unroll
            for (int ks = 0; ks < 4; ks++) {
                float4 x0 = *(const float4*)&ap[ks * 32 + l4 * 8];
                float4 x1 = *(const float4*)&ap[ks * 32 + l4 * 8 + 4];
                bf16x8 a = {f2bf(x0.x), f2bf(x0.y), f2bf(x0.z), f2bf(x0.w),
                            f2bf(x1.x), f2bf(x1.y), f2bf(x1.z), f2bf(x1.w)};
                acc0 = __builtin_amdgcn_mfma_f32_16x16x32_bf16(a, bw[0][ks], acc0, 0, 0, 0);
                acc1 = __builtin_amdgcn_mfma_f32_16x16x32_bf16(a, bw[1][ks], acc1, 0, 0, 0);
            }
#pragma unroll
            for (int r = 0; r < 4; r++) {
                int er = m * 16 + l4 * 4 + r;
                t1_s[er * 136 + n0 + l15] = f2bf(ssp(acc0[r]));
                t1_s[er * 136 + n0 + 16 + l15] = f2bf(ssp(acc1[r]));
            }
        }
    }
    __syncthreads();

    // GEMM2: v_new = v + (t1 @ u2 + ub2)
    {
        bf16x8 bw[2][4];
        float bias[2];
#pragma unroll
        for (int n = 0; n < 2; n++) {
            bias[n] = ub2[n0 + n * 16 + l15];
#pragma unroll
            for (int ks = 0; ks < 4; ks++)
                bw[n][ks] = *(const bf16x8*)&u2t[(n0 + n * 16 + l15) * 128 + ks * 32 + l4 * 8];
        }
#pragma unroll
        for (int m = 0; m < 2; m++) {
            f32x4 acc0 = {bias[0], bias[0], bias[0], bias[0]};
            f32x4 acc1 = {bias[1], bias[1], bias[1], bias[1]};
#pragma unroll
            for (int ks = 0; ks < 4; ks++) {
                bf16x8 a = *(const bf16x8*)&t1_s[(m * 16 + l15) * 136 + ks * 32 + l4 * 8];
                acc0 = __builtin_amdgcn_mfma_f32_16x16x32_bf16(a, bw[0][ks], acc0, 0, 0, 0);
                acc1 = __builtin_amdgcn_mfma_f32_16x16x32_bf16(a, bw[1][ks], acc1, 0, 0, 0);
            }
#pragma unroll
            for (int r = 0; r < 4; r++) {
                int er = m * 16 + l4 * 4 + r;
                int gn = nb0 + er;
                if (gn < N_) {
                    size_t i0 = (size_t)gn * HH + n0 + l15;
                    size_t i1 = (size_t)gn * HH + n0 + 16 + l15;
                    float v0 = vb[i0] + acc0[r];
                    float v1 = vb[i1] + acc1[r];
                    vb[i0] = v0;
                    vb[i1] = v1;
                    t2_s[er * 136 + n0 + l15] = f2bf(v0);
                    t2_s[er * 136 + n0 + 16 + l15] = f2bf(v1);
                } else {
                    t2_s[er * 136 + n0 + l15] = 0;
                    t2_s[er * 136 + n0 + 16 + l15] = 0;
                }
            }
        }
    }
    __syncthreads();

    // GEMM3: vproj_next = v_new @ lin_w[l+1] (bf16 out)
    if (lwt_next) {
        bf16x8 bw[2][4];
#pragma unroll
        for (int n = 0; n < 2; n++)
#pragma unroll
            for (int ks = 0; ks < 4; ks++)
                bw[n][ks] = *(const bf16x8*)&lwt_next[(n0 + n * 16 + l15) * 128 + ks * 32 + l4 * 8];
#pragma unroll
        for (int m = 0; m < 2; m++) {
            f32x4 acc0 = {0.f, 0.f, 0.f, 0.f}, acc1 = {0.f, 0.f, 0.f, 0.f};
#pragma unroll
            for (int ks = 0; ks < 4; ks++) {
                bf16x8 a = *(const bf16x8*)&t2_s[(m * 16 + l15) * 136 + ks * 32 + l4 * 8];
                acc0 = __builtin_amdgcn_mfma_f32_16x16x32_bf16(a, bw[0][ks], acc0, 0, 0, 0);
                acc1 = __builtin_amdgcn_mfma_f32_16x16x32_bf16(a, bw[1][ks], acc1, 0, 0, 0);
            }
#pragma unroll
            for (int r = 0; r < 4; r++) {
                int gn = nb0 + m * 16 + l4 * 4 + r;
                if (gn < N_) {
                    vproj[(size_t)gn * FF + n0 + l15] = (unsigned short)f2bf(acc0[r]);
                    vproj[(size_t)gn * FF + n0 + 16 + l15] = (unsigned short)f2bf(acc1[r]);
                }
            }
        }
    }
}

extern "C" void kernel_launch(void* const* d_in, const int* in_sizes, int n_in,
                              void* d_out, int out_size, void* d_ws, size_t ws_size,
                              hipStream_t stream) {
    const float* v = (const float*)d_in[0];
    const float* pos = (const float*)d_in[1];
    const float* offs = (const float*)d_in[2];
    const int* edges = (const int*)d_in[3];
    const float* lin_w = (const float*)d_in[4];
    const float* w1 = (const float*)d_in[5];
    const float* b1 = (const float*)d_in[6];
    const float* w2 = (const float*)d_in[7];
    const float* b2 = (const float*)d_in[8];
    const float* u1 = (const float*)d_in[9];
    const float* ub1 = (const float*)d_in[10];
    const float* u2 = (const float*)d_in[11];
    const float* ub2 = (const float*)d_in[12];

    const int N = in_sizes[0] / HH;
    const int E = in_sizes[3] / 2;
    const int* row = edges;
    const int* col = edges + E;

    char* base = (char*)d_ws;
    int* counts = (int*)base;    base += (size_t)N * 4;
    int* woff = (int*)base;      base += (size_t)N * 4;
    int* offsets = (int*)base;   base += (size_t)N * 4;
    int* srow = (int*)base;      base += (size_t)E * 4;
    float* sdist = (float*)base; base += (size_t)E * 4;
    float* sCb = (float*)base;   base += (size_t)E * 4;
    float* vbuf = (float*)base;  base += (size_t)N * HH * 4;
    unsigned short* vproj = (unsigned short*)base; base += (size_t)N * FF * 2;
    short* w1t = (short*)base;   base += (size_t)NLAYERS * FF * 64 * 2;
    short* w2t = (short*)base;   base += (size_t)NLAYERS * FF * FF * 2;
    short* u1t = (short*)base;   base += (size_t)NLAYERS * FF * FF * 2;
    short* u2t = (short*)base;   base += (size_t)NLAYERS * FF * FF * 2;
    short* lin_wt = (short*)base; base += (size_t)NLAYERS * FF * FF * 2;
    unsigned short* msg = (unsigned short*)base;   // E*128 bf16 = 82 MB

    const int EB = (E + 255) / 256;
    const int NB64 = (N + 63) / 64;
    const int NB32 = (N + 31) / 32;

    hipMemsetAsync(counts, 0, (size_t)N * 4, stream);
    hist_kernel<<<EB, 256, 0, stream>>>(col, counts, E);
    scan_kernel<<<1, 1024, 0, stream>>>(counts, offsets, woff, N);
    scatter_kernel<<<EB, 256, 0, stream>>>(pos, offs, row, col, woff, srow,
                                           sdist, sCb, E);
    prep_kernel<<<(NLAYERS * FF * FF + 255) / 256, 256, 0, stream>>>(
        w1, w2, u1, u2, lin_w, w1t, w2t, u1t, u2t, lin_wt);
    hipMemcpyAsync(vbuf, v, (size_t)N * HH * sizeof(float),
                   hipMemcpyDeviceToDevice, stream);
    vproj0_kernel<<<NB64, 256, 0, stream>>>(v, lin_wt, vproj, N);

    for (int l = 0; l < NLAYERS; l++) {
        edge_mfma_kernel<<<(E + 63) / 64, 256, 0, stream>>>(
            sdist, sCb, vproj, srow, w1t + (size_t)l * FF * 64,
            b1 + (size_t)l * FF, w2t + (size_t)l * FF * FF, b2 + (size_t)l * FF,
            msg, E);
        node_mfma_kernel<<<NB32, 256, 0, stream>>>(
            msg, offsets, woff, u1t + (size_t)l * FF * FF, ub1 + (size_t)l * HH,
            u2t + (size_t)l * FF * FF, ub2 + (size_t)l * HH, vbuf,
            (l + 1 < NLAYERS) ? (lin_wt + (size_t)(l + 1) * FF * FF) : nullptr,
            vproj, N);
    }
    hipMemcpyAsync(d_out, vbuf, (size_t)N * HH * sizeof(float),
                   hipMemcpyDeviceToDevice, stream);
}

// Round 8
// 1048.874 us; speedup vs baseline: 1.0066x; 1.0066x over previous
//
#include <hip/hip_runtime.h>
#include <hip/hip_bf16.h>
#include <math.h>

#define HH 128
#define FF 128
#define GG 50
#define NLAYERS 6

typedef __attribute__((ext_vector_type(8))) short bf16x8;
typedef __attribute__((ext_vector_type(4))) float f32x4;

static __device__ __forceinline__ float ssp(float x) {
    return fmaxf(x, 0.f) + __logf(1.f + __expf(-fabsf(x))) - 0.6931471805599453f;
}

static __device__ __forceinline__ short f2bf(float x) {
    union { float f; unsigned u; } c; c.f = x;
    unsigned r = (c.u + 0x7FFF + ((c.u >> 16) & 1)) >> 16;
    return (short)r;
}

static __device__ __forceinline__ float bf2f(unsigned short x) {
    union { unsigned u; float f; } c; c.u = ((unsigned)x) << 16; return c.f;
}
static __device__ __forceinline__ float bf2f_lo(unsigned p) {
    union { unsigned u; float f; } c; c.u = p << 16; return c.f;
}
static __device__ __forceinline__ float bf2f_hi(unsigned p) {
    union { unsigned u; float f; } c; c.u = p & 0xFFFF0000u; return c.f;
}

// ---------------- sort pipeline: hist -> scan -> scatter ----------------
__global__ void hist_kernel(const int* __restrict__ col, int* __restrict__ counts, int E_) {
    int e = blockIdx.x * 256 + threadIdx.x;
    if (e < E_) atomicAdd(&counts[col[e]], 1);
}

// writes exclusive prefix into BOTH offsets (kept) and woff (mutated by scatter)
__global__ __launch_bounds__(1024) void scan_kernel(const int* __restrict__ counts,
                                                    int* __restrict__ offsets,
                                                    int* __restrict__ woff, int N_) {
    __shared__ int wsum[16];
    __shared__ int carry_s;
    const int tid = threadIdx.x;
    const int lane = tid & 63, wid = tid >> 6;
    if (tid == 0) carry_s = 0;
    __syncthreads();
    for (int base = 0; base < N_; base += 1024) {
        int i = base + tid;
        int val = (i < N_) ? counts[i] : 0;
        int x = val;
#pragma unroll
        for (int d = 1; d < 64; d <<= 1) {
            int t = __shfl_up(x, d, 64);
            if (lane >= d) x += t;
        }
        if (lane == 63) wsum[wid] = x;
        int carry = carry_s;
        __syncthreads();
        if (wid == 0) {
            int s = (lane < 16) ? wsum[lane] : 0;
#pragma unroll
            for (int d = 1; d < 16; d <<= 1) {
                int t = __shfl_up(s, d, 64);
                if (lane >= d) s += t;
            }
            if (lane < 16) wsum[lane] = s;
            if (lane == 15) carry_s = carry + s;
        }
        __syncthreads();
        int woffset = (wid > 0) ? wsum[wid - 1] : 0;
        if (i < N_) {
            int ex = carry + woffset + x - val;  // exclusive
            offsets[i] = ex;
            woff[i] = ex;
        }
        __syncthreads();
    }
}

__global__ void scatter_kernel(const float* __restrict__ pos,
                               const float* __restrict__ offs,
                               const int* __restrict__ row,
                               const int* __restrict__ col,
                               int* __restrict__ woff,
                               int* __restrict__ srow,
                               float* __restrict__ sdist, float* __restrict__ sCb,
                               int E_) {
    int e = blockIdx.x * 256 + threadIdx.x;
    if (e >= E_) return;
    int r = row[e], c = col[e];
    float dx = pos[c * 3 + 0] + offs[e * 3 + 0] - pos[r * 3 + 0];
    float dy = pos[c * 3 + 1] + offs[e * 3 + 1] - pos[r * 3 + 1];
    float dz = pos[c * 3 + 2] + offs[e * 3 + 2] - pos[r * 3 + 2];
    float d = sqrtf(dx * dx + dy * dy + dz * dz);
    int p = atomicAdd(&woff[c], 1);
    srow[p] = r;
    sdist[p] = d;
    sCb[p] = 0.5f * (cosf(d * 0.6283185307179586f) + 1.0f);
}

// ------------- prep: transpose + bf16 all weights (all layers) -------------
__global__ __launch_bounds__(256) void prep_kernel(
    const float* __restrict__ w1, const float* __restrict__ w2,
    const float* __restrict__ u1, const float* __restrict__ u2,
    const float* __restrict__ lin_w,
    short* __restrict__ w1t, short* __restrict__ w2t,
    short* __restrict__ u1t, short* __restrict__ u2t, short* __restrict__ lin_wt) {
    int idx = blockIdx.x * 256 + threadIdx.x;
    if (idx < NLAYERS * FF * FF) {
        int l = idx >> 14, r = idx & 16383, a = r >> 7, b = r & 127;
        size_t src = (size_t)l * FF * FF + (size_t)b * FF + a;  // [l][b][a]
        w2t[idx] = f2bf(w2[src]);
        u1t[idx] = f2bf(u1[src]);
        u2t[idx] = f2bf(u2[src]);
        lin_wt[idx] = f2bf(lin_w[src]);
    }
    if (idx < NLAYERS * FF * 64) {
        int l = idx >> 13, r = idx & 8191, fo = r >> 6, g = r & 63;
        w1t[idx] = f2bf(g < GG ? w1[((size_t)l * GG + g) * FF + fo] : 0.f);
    }
}

// ---------------- vproj0 = v(f32) @ lin_w[0]  via MFMA, bf16 out ----------------
__global__ __launch_bounds__(256) void vproj0_kernel(const float* __restrict__ vb,
                                                     const short* __restrict__ lwt,
                                                     unsigned short* __restrict__ out,
                                                     int N_) {
    const int tid = threadIdx.x;
    const int lane = tid & 63, wave = tid >> 6;
    const int l15 = lane & 15, l4 = lane >> 4;
    const int n0 = wave * 32;
    const int nb0 = blockIdx.x * 64;
    bf16x8 bw[2][4];
#pragma unroll
    for (int n = 0; n < 2; n++)
#pragma unroll
        for (int ks = 0; ks < 4; ks++)
            bw[n][ks] = *(const bf16x8*)&lwt[(n0 + n * 16 + l15) * 128 + ks * 32 + l4 * 8];
#pragma unroll
    for (int m = 0; m < 4; m++) {
        f32x4 acc0 = {0.f, 0.f, 0.f, 0.f}, acc1 = {0.f, 0.f, 0.f, 0.f};
        int arow = nb0 + m * 16 + l15;
        const float* ap = &vb[(size_t)(arow < N_ ? arow : 0) * HH];
#pragma unroll
        for (int ks = 0; ks < 4; ks++) {
            float4 x0 = *(const float4*)&ap[ks * 32 + l4 * 8];
            float4 x1 = *(const float4*)&ap[ks * 32 + l4 * 8 + 4];
            bf16x8 a = {f2bf(x0.x), f2bf(x0.y), f2bf(x0.z), f2bf(x0.w),
                        f2bf(x1.x), f2bf(x1.y), f2bf(x1.z), f2bf(x1.w)};
            acc0 = __builtin_amdgcn_mfma_f32_16x16x32_bf16(a, bw[0][ks], acc0, 0, 0, 0);
            acc1 = __builtin_amdgcn_mfma_f32_16x16x32_bf16(a, bw[1][ks], acc1, 0, 0, 0);
        }
#pragma unroll
        for (int r = 0; r < 4; r++) {
            int gn = nb0 + m * 16 + l4 * 4 + r;
            if (gn < N_) {
                out[(size_t)gn * FF + n0 + l15] = (unsigned short)f2bf(acc0[r]);
                out[(size_t)gn * FF + n0 + 16 + l15] = (unsigned short)f2bf(acc1[r]);
            }
        }
    }
}

// ---------------- fused edge kernel: MFMA filter + msg materialization ----------------
// LDS = union(h1, wf) ~17.4 KB -> 8 blocks/CU. No atomics.
// Epilogue: wave-per-edge loop; every global access = 256B wave-contiguous.
__global__ __launch_bounds__(256, 8) void edge_mfma_kernel(
    const float* __restrict__ sdist, const float* __restrict__ sCb,
    const unsigned short* __restrict__ vproj, const int* __restrict__ srow,
    const short* __restrict__ w1t, const float* __restrict__ b1,
    const short* __restrict__ w2t, const float* __restrict__ b2,
    unsigned short* __restrict__ msg, int E_) {
    __shared__ __align__(16) short lds_pool[64 * 136];
    __shared__ int srow_s[64];
    short* h1_s = lds_pool;                               // [64][136]
    unsigned short* wf_s = (unsigned short*)lds_pool;     // [64][132] alias
    const int tid = threadIdx.x;
    const int lane = tid & 63, wave = tid >> 6;
    const int l15 = lane & 15, l4 = lane >> 4;
    const int n0 = wave * 32;
    const int e0 = blockIdx.x * 64;

    bf16x8 bw1[2][2], bw2[2][4];
    float bias1[2], bias2[2];
#pragma unroll
    for (int n = 0; n < 2; n++) {
        const int fo = n0 + n * 16 + l15;
        bias1[n] = b1[fo];
        bias2[n] = b2[fo];
#pragma unroll
        for (int ks = 0; ks < 2; ks++)
            bw1[n][ks] = *(const bf16x8*)&w1t[fo * 64 + ks * 32 + l4 * 8];
#pragma unroll
        for (int ks = 0; ks < 4; ks++)
            bw2[n][ks] = *(const bf16x8*)&w2t[fo * 128 + ks * 32 + l4 * 8];
    }

    if (tid < 64) {
        int ge = e0 + tid;
        if (ge >= E_) ge = E_ - 1;
        srow_s[tid] = srow[ge];
    }

    // GEMM1: h1 = ssp(demb @ w1 + b1), demb computed in registers
    const float STEP = 5.0f / 49.0f;
    const float COEFF = -0.5f / (STEP * STEP);
#pragma unroll
    for (int m = 0; m < 4; m++) {
        int ge = e0 + m * 16 + l15;
        float d = sdist[ge < E_ ? ge : 0];
        bf16x8 a0, a1;
#pragma unroll
        for (int j = 0; j < 8; j++) {
            int g0 = l4 * 8 + j;                       // 0..31
            float x0 = fmaf((float)g0, -STEP, d);
            a0[j] = f2bf(__expf(COEFF * x0 * x0));
            int g1 = 32 + l4 * 8 + j;                  // 32..63
            float x1 = fmaf((float)g1, -STEP, d);
            a1[j] = (g1 < GG) ? f2bf(__expf(COEFF * x1 * x1)) : (short)0;
        }
#pragma unroll
        for (int n = 0; n < 2; n++) {
            f32x4 acc = {bias1[n], bias1[n], bias1[n], bias1[n]};
            acc = __builtin_amdgcn_mfma_f32_16x16x32_bf16(a0, bw1[n][0], acc, 0, 0, 0);
            acc = __builtin_amdgcn_mfma_f32_16x16x32_bf16(a1, bw1[n][1], acc, 0, 0, 0);
            const int f = n0 + n * 16 + l15;
#pragma unroll
            for (int r = 0; r < 4; r++)
                h1_s[(m * 16 + l4 * 4 + r) * 136 + f] = f2bf(ssp(acc[r]));
        }
    }
    __syncthreads();

    // GEMM2 into registers
    f32x4 accA[4], accB[4];
#pragma unroll
    for (int m = 0; m < 4; m++) {
        accA[m] = {bias2[0], bias2[0], bias2[0], bias2[0]};
        accB[m] = {bias2[1], bias2[1], bias2[1], bias2[1]};
#pragma unroll
        for (int ks = 0; ks < 4; ks++) {
            bf16x8 a = *(const bf16x8*)&h1_s[(m * 16 + l15) * 136 + ks * 32 + l4 * 8];
            accA[m] = __builtin_amdgcn_mfma_f32_16x16x32_bf16(a, bw2[0][ks], accA[m], 0, 0, 0);
            accB[m] = __builtin_amdgcn_mfma_f32_16x16x32_bf16(a, bw2[1][ks], accB[m], 0, 0, 0);
        }
    }
    __syncthreads();  // all h1 reads done; wf_s may alias

    // store Wf * C to LDS (bf16)
#pragma unroll
    for (int m = 0; m < 4; m++) {
#pragma unroll
        for (int r = 0; r < 4; r++) {
            int er = m * 16 + l4 * 4 + r;
            int ge = e0 + er;
            float cb = (ge < E_) ? sCb[ge] : 0.f;
            wf_s[er * 132 + n0 + l15] = (unsigned short)f2bf(accA[m][r] * cb);
            wf_s[er * 132 + n0 + 16 + l15] = (unsigned short)f2bf(accB[m][r] * cb);
        }
    }
    __syncthreads();

    // msg epilogue: wave w owns edges [16w, 16w+16); lane t = feature pair (2t,2t+1)
    // gather read: 256B wave-contiguous; msg store: 256B wave-contiguous line-aligned
    {
        const int t = lane;
        for (int i = 0; i < 16; i++) {
            int e = wave * 16 + i;
            int ge = e0 + e;
            if (ge >= E_) break;   // wave-uniform (edges ascending)
            int r_ = srow_s[e];
            unsigned vp = *(const unsigned*)&vproj[(size_t)r_ * FF + 2 * t];
            unsigned wp = *(const unsigned*)&wf_s[e * 132 + 2 * t];
            float p0 = bf2f_lo(wp) * bf2f_lo(vp);
            float p1 = bf2f_hi(wp) * bf2f_hi(vp);
            unsigned outw = ((unsigned)(unsigned short)f2bf(p0)) |
                            (((unsigned)(unsigned short)f2bf(p1)) << 16);
            *(unsigned*)&msg[(size_t)ge * FF + 2 * t] = outw;
        }
    }
}

// ------- node kernel: CSR segment-sum of msg -> LDS agg; MLP; vproj_next -------
__global__ __launch_bounds__(256) void node_mfma_kernel(
    const unsigned short* __restrict__ msg, const int* __restrict__ off_start,
    const int* __restrict__ off_end, const short* __restrict__ u1t,
    const float* __restrict__ ub1, const short* __restrict__ u2t,
    const float* __restrict__ ub2, float* __restrict__ vb,
    const short* __restrict__ lwt_next, unsigned short* __restrict__ vproj, int N_) {
    __shared__ __align__(16) float agg_s[32][132];
    __shared__ __align__(16) short t1_s[32 * 136];
    __shared__ __align__(16) short t2_s[32 * 136];
    const int tid = threadIdx.x;
    const int lane = tid & 63, wave = tid >> 6;
    const int l15 = lane & 15, l4 = lane >> 4;
    const int n0 = wave * 32;
    const int nb0 = blockIdx.x * 32;

    // ---- CSR aggregation: wave w sums nodes nb0 + w*8 .. +8 (deterministic order)
    {
        const int t = lane;   // feature pair index: features 2t, 2t+1
        for (int s = 0; s < 8; s++) {
            int nl = wave * 8 + s;
            int n = nb0 + nl;
            float a0 = 0.f, a1 = 0.f;
            if (n < N_) {
                int e = off_start[n];
                const int eend = off_end[n];
                for (; e + 1 < eend; e += 2) {
                    unsigned p0 = *(const unsigned*)&msg[(size_t)e * FF + 2 * t];
                    unsigned p1 = *(const unsigned*)&msg[(size_t)(e + 1) * FF + 2 * t];
                    a0 += bf2f_lo(p0) + bf2f_lo(p1);
                    a1 += bf2f_hi(p0) + bf2f_hi(p1);
                }
                if (e < eend) {
                    unsigned p0 = *(const unsigned*)&msg[(size_t)e * FF + 2 * t];
                    a0 += bf2f_lo(p0);
                    a1 += bf2f_hi(p0);
                }
            }
            agg_s[nl][2 * t] = a0;
            agg_s[nl][2 * t + 1] = a1;
        }
    }
    __syncthreads();

    // GEMM1: t1 = ssp(agg @ u1 + ub1)
    {
        bf16x8 bw[2][4];
        float bias[2];
#pragma unroll
        for (int n = 0; n < 2; n++) {
            bias[n] = ub1[n0 + n * 16 + l15];
#pragma unroll
            for (int ks = 0; ks < 4; ks++)
                bw[n][ks] = *(const bf16x8*)&u1t[(n0 + n * 16 + l15) * 128 + ks * 32 + l4 * 8];
        }
#pragma unroll
        for (int m = 0; m < 2; m++) {
            const float* ap = &agg_s[m * 16 + l15][0];
            f32x4 acc0 = {bias[0], bias[0], bias[0], bias[0]};
            f32x4 acc1 = {bias[1], bias[1], bias[1], bias[1]};
#pragma unroll
            for (int ks = 0; ks < 4; ks++) {
                float4 x0 = *(const float4*)&ap[ks * 32 + l4 * 8];
                float4 x1 = *(const float4*)&ap[ks * 32 + l4 * 8 + 4];
                bf16x8 a = {f2bf(x0.x), f2bf(x0.y), f2bf(x0.z), f2bf(x0.w),
                            f2bf(x1.x), f2bf(x1.y), f2bf(x1.z), f2bf(x1.w)};
                acc0 = __builtin_amdgcn_mfma_f32_16x16x32_bf16(a, bw[0][ks], acc0, 0, 0, 0);
                acc1 = __builtin_amdgcn_mfma_f32_16x16x32_bf16(a, bw[1][ks], acc1, 0, 0, 0);
            }
#pragma unroll
            for (int r = 0; r < 4; r++) {
                int er = m * 16 + l4 * 4 + r;
                t1_s[er * 136 + n0 + l15] = f2bf(ssp(acc0[r]));
                t1_s[er * 136 + n0 + 16 + l15] = f2bf(ssp(acc1[r]));
            }
        }
    }
    __syncthreads();

    // GEMM2: v_new = v + (t1 @ u2 + ub2)
    {
        bf16x8 bw[2][4];
        float bias[2];
#pragma unroll
        for (int n = 0; n < 2; n++) {
            bias[n] = ub2[n0 + n * 16 + l15];
#pragma unroll
            for (int ks = 0; ks < 4; ks++)
                bw[n][ks] = *(const bf16x8*)&u2t[(n0 + n * 16 + l15) * 128 + ks * 32 + l4 * 8];
        }
#pragma unroll
        for (int m = 0; m < 2; m++) {
            f32x4 acc0 = {bias[0], bias[0], bias[0], bias[0]};
            f32x4 acc1 = {bias[1], bias[1], bias[1], bias[1]};
#pragma unroll
            for (int ks = 0; ks < 4; ks++) {
                bf16x8 a = *(const bf16x8*)&t1_s[(m * 16 + l15) * 136 + ks * 32 + l4 * 8];
                acc0 = __builtin_amdgcn_mfma_f32_16x16x32_bf16(a, bw[0][ks], acc0, 0, 0, 0);
                acc1 = __builtin_amdgcn_mfma_f32_16x16x32_bf16(a, bw[1][ks], acc1, 0, 0, 0);
            }
#pragma unroll
            for (int r = 0; r < 4; r++) {
                int er = m * 16 + l4 * 4 + r;
                int gn = nb0 + er;
                if (gn < N_) {
                    size_t i0 = (size_t)gn * HH + n0 + l15;
                    size_t i1 = (size_t)gn * HH + n0 + 16 + l15;
                    float v0 = vb[i0] + acc0[r];
                    float v1 = vb[i1] + acc1[r];
                    vb[i0] = v0;
                    vb[i1] = v1;
                    t2_s[er * 136 + n0 + l15] = f2bf(v0);
                    t2_s[er * 136 + n0 + 16 + l15] = f2bf(v1);
                } else {
                    t2_s[er * 136 + n0 + l15] = 0;
                    t2_s[er * 136 + n0 + 16 + l15] = 0;
                }
            }
        }
    }
    __syncthreads();

    // GEMM3: vproj_next = v_new @ lin_w[l+1] (bf16 out)
    if (lwt_next) {
        bf16x8 bw[2][4];
#pragma unroll
        for (int n = 0; n < 2; n++)
#pragma unroll
            for (int ks = 0; ks < 4; ks++)
                bw[n][ks] = *(const bf16x8*)&lwt_next[(n0 + n * 16 + l15) * 128 + ks * 32 + l4 * 8];
#pragma unroll
        for (int m = 0; m < 2; m++) {
            f32x4 acc0 = {0.f, 0.f, 0.f, 0.f}, acc1 = {0.f, 0.f, 0.f, 0.f};
#pragma unroll
            for (int ks = 0; ks < 4; ks++) {
                bf16x8 a = *(const bf16x8*)&t2_s[(m * 16 + l15) * 136 + ks * 32 + l4 * 8];
                acc0 = __builtin_amdgcn_mfma_f32_16x16x32_bf16(a, bw[0][ks], acc0, 0, 0, 0);
                acc1 = __builtin_amdgcn_mfma_f32_16x16x32_bf16(a, bw[1][ks], acc1, 0, 0, 0);
            }
#pragma unroll
            for (int r = 0; r < 4; r++) {
                int gn = nb0 + m * 16 + l4 * 4 + r;
                if (gn < N_) {
                    vproj[(size_t)gn * FF + n0 + l15] = (unsigned short)f2bf(acc0[r]);
                    vproj[(size_t)gn * FF + n0 + 16 + l15] = (unsigned short)f2bf(acc1[r]);
                }
            }
        }
    }
}

extern "C" void kernel_launch(void* const* d_in, const int* in_sizes, int n_in,
                              void* d_out, int out_size, void* d_ws, size_t ws_size,
                              hipStream_t stream) {
    const float* v = (const float*)d_in[0];
    const float* pos = (const float*)d_in[1];
    const float* offs = (const float*)d_in[2];
    const int* edges = (const int*)d_in[3];
    const float* lin_w = (const float*)d_in[4];
    const float* w1 = (const float*)d_in[5];
    const float* b1 = (const float*)d_in[6];
    const float* w2 = (const float*)d_in[7];
    const float* b2 = (const float*)d_in[8];
    const float* u1 = (const float*)d_in[9];
    const float* ub1 = (const float*)d_in[10];
    const float* u2 = (const float*)d_in[11];
    const float* ub2 = (const float*)d_in[12];

    const int N = in_sizes[0] / HH;
    const int E = in_sizes[3] / 2;
    const int* row = edges;
    const int* col = edges + E;

    char* base = (char*)d_ws;
    int* counts = (int*)base;    base += (size_t)N * 4;
    int* woff = (int*)base;      base += (size_t)N * 4;
    int* offsets = (int*)base;   base += (size_t)N * 4;
    int* srow = (int*)base;      base += (size_t)E * 4;
    float* sdist = (float*)base; base += (size_t)E * 4;
    float* sCb = (float*)base;   base += (size_t)E * 4;
    float* vbuf = (float*)base;  base += (size_t)N * HH * 4;
    unsigned short* vproj = (unsigned short*)base; base += (size_t)N * FF * 2;
    short* w1t = (short*)base;   base += (size_t)NLAYERS * FF * 64 * 2;
    short* w2t = (short*)base;   base += (size_t)NLAYERS * FF * FF * 2;
    short* u1t = (short*)base;   base += (size_t)NLAYERS * FF * FF * 2;
    short* u2t = (short*)base;   base += (size_t)NLAYERS * FF * FF * 2;
    short* lin_wt = (short*)base; base += (size_t)NLAYERS * FF * FF * 2;
    unsigned short* msg = (unsigned short*)base;   // E*128 bf16 = 82 MB

    const int EB = (E + 255) / 256;
    const int NB64 = (N + 63) / 64;
    const int NB32 = (N + 31) / 32;

    hipMemsetAsync(counts, 0, (size_t)N * 4, stream);
    hist_kernel<<<EB, 256, 0, stream>>>(col, counts, E);
    scan_kernel<<<1, 1024, 0, stream>>>(counts, offsets, woff, N);
    scatter_kernel<<<EB, 256, 0, stream>>>(pos, offs, row, col, woff, srow,
                                           sdist, sCb, E);
    prep_kernel<<<(NLAYERS * FF * FF + 255) / 256, 256, 0, stream>>>(
        w1, w2, u1, u2, lin_w, w1t, w2t, u1t, u2t, lin_wt);
    hipMemcpyAsync(vbuf, v, (size_t)N * HH * sizeof(float),
                   hipMemcpyDeviceToDevice, stream);
    vproj0_kernel<<<NB64, 256, 0, stream>>>(v, lin_wt, vproj, N);

    for (int l = 0; l < NLAYERS; l++) {
        edge_mfma_kernel<<<(E + 63) / 64, 256, 0, stream>>>(
            sdist, sCb, vproj, srow, w1t + (size_t)l * FF * 64,
            b1 + (size_t)l * FF, w2t + (size_t)l * FF * FF, b2 + (size_t)l * FF,
            msg, E);
        node_mfma_kernel<<<NB32, 256, 0, stream>>>(
            msg, offsets, woff, u1t + (size_t)l * FF * FF, ub1 + (size_t)l * HH,
            u2t + (size_t)l * FF * FF, ub2 + (size_t)l * HH, vbuf,
            (l + 1 < NLAYERS) ? (lin_wt + (size_t)(l + 1) * FF * FF) : nullptr,
            vproj, N);
    }
    hipMemcpyAsync(d_out, vbuf, (size_t)N * HH * sizeof(float),
                   hipMemcpyDeviceToDevice, stream);
}

// Round 9
// 1040.310 us; speedup vs baseline: 1.0149x; 1.0082x over previous
//
#include <hip/hip_runtime.h>
#include <hip/hip_bf16.h>
#include <math.h>

#define HH 128
#define FF 128
#define GG 50
#define NLAYERS 6
#define NPB 32   // nodes per block
#define ET 64    // edge tile

typedef __attribute__((ext_vector_type(8))) short bf16x8;
typedef __attribute__((ext_vector_type(4))) float f32x4;

static __device__ __forceinline__ float ssp(float x) {
    return fmaxf(x, 0.f) + __logf(1.f + __expf(-fabsf(x))) - 0.6931471805599453f;
}

static __device__ __forceinline__ short f2bf(float x) {
    union { float f; unsigned u; } c; c.f = x;
    unsigned r = (c.u + 0x7FFF + ((c.u >> 16) & 1)) >> 16;
    return (short)r;
}

static __device__ __forceinline__ float bf2f_lo(unsigned p) {
    union { unsigned u; float f; } c; c.u = p << 16; return c.f;
}
static __device__ __forceinline__ float bf2f_hi(unsigned p) {
    union { unsigned u; float f; } c; c.u = p & 0xFFFF0000u; return c.f;
}

// ---------------- sort pipeline: hist -> scan -> scatter ----------------
__global__ void hist_kernel(const int* __restrict__ col, int* __restrict__ counts, int E_) {
    int e = blockIdx.x * 256 + threadIdx.x;
    if (e < E_) atomicAdd(&counts[col[e]], 1);
}

__global__ __launch_bounds__(1024) void scan_kernel(const int* __restrict__ counts,
                                                    int* __restrict__ offsets,
                                                    int* __restrict__ woff, int N_) {
    __shared__ int wsum[16];
    __shared__ int carry_s;
    const int tid = threadIdx.x;
    const int lane = tid & 63, wid = tid >> 6;
    if (tid == 0) carry_s = 0;
    __syncthreads();
    for (int base = 0; base < N_; base += 1024) {
        int i = base + tid;
        int val = (i < N_) ? counts[i] : 0;
        int x = val;
#pragma unroll
        for (int d = 1; d < 64; d <<= 1) {
            int t = __shfl_up(x, d, 64);
            if (lane >= d) x += t;
        }
        if (lane == 63) wsum[wid] = x;
        int carry = carry_s;
        __syncthreads();
        if (wid == 0) {
            int s = (lane < 16) ? wsum[lane] : 0;
#pragma unroll
            for (int d = 1; d < 16; d <<= 1) {
                int t = __shfl_up(s, d, 64);
                if (lane >= d) s += t;
            }
            if (lane < 16) wsum[lane] = s;
            if (lane == 15) carry_s = carry + s;
        }
        __syncthreads();
        int woffset = (wid > 0) ? wsum[wid - 1] : 0;
        if (i < N_) {
            int ex = carry + woffset + x - val;  // exclusive
            offsets[i] = ex;
            woff[i] = ex;
        }
        __syncthreads();
    }
}

__global__ void scatter_kernel(const float* __restrict__ pos,
                               const float* __restrict__ offs,
                               const int* __restrict__ row,
                               const int* __restrict__ col,
                               int* __restrict__ woff,
                               int* __restrict__ srow, int* __restrict__ scol,
                               float* __restrict__ sdist, float* __restrict__ sCb,
                               int E_) {
    int e = blockIdx.x * 256 + threadIdx.x;
    if (e >= E_) return;
    int r = row[e], c = col[e];
    float dx = pos[c * 3 + 0] + offs[e * 3 + 0] - pos[r * 3 + 0];
    float dy = pos[c * 3 + 1] + offs[e * 3 + 1] - pos[r * 3 + 1];
    float dz = pos[c * 3 + 2] + offs[e * 3 + 2] - pos[r * 3 + 2];
    float d = sqrtf(dx * dx + dy * dy + dz * dz);
    int p = atomicAdd(&woff[c], 1);
    srow[p] = r;
    scol[p] = c;
    sdist[p] = d;
    sCb[p] = 0.5f * (cosf(d * 0.6283185307179586f) + 1.0f);
}

// ------------- prep: transpose + bf16 all weights (all layers) -------------
__global__ __launch_bounds__(256) void prep_kernel(
    const float* __restrict__ w1, const float* __restrict__ w2,
    const float* __restrict__ u1, const float* __restrict__ u2,
    const float* __restrict__ lin_w,
    short* __restrict__ w1t, short* __restrict__ w2t,
    short* __restrict__ u1t, short* __restrict__ u2t, short* __restrict__ lin_wt) {
    int idx = blockIdx.x * 256 + threadIdx.x;
    if (idx < NLAYERS * FF * FF) {
        int l = idx >> 14, r = idx & 16383, a = r >> 7, b = r & 127;
        size_t src = (size_t)l * FF * FF + (size_t)b * FF + a;  // [l][b][a]
        w2t[idx] = f2bf(w2[src]);
        u1t[idx] = f2bf(u1[src]);
        u2t[idx] = f2bf(u2[src]);
        lin_wt[idx] = f2bf(lin_w[src]);
    }
    if (idx < NLAYERS * FF * 64) {
        int l = idx >> 13, r = idx & 8191, fo = r >> 6, g = r & 63;
        w1t[idx] = f2bf(g < GG ? w1[((size_t)l * GG + g) * FF + fo] : 0.f);
    }
}

// ---------------- vproj0 = v(f32) @ lin_w[0]  via MFMA, bf16 out ----------------
__global__ __launch_bounds__(256) void vproj0_kernel(const float* __restrict__ vb,
                                                     const short* __restrict__ lwt,
                                                     unsigned short* __restrict__ out,
                                                     int N_) {
    const int tid = threadIdx.x;
    const int lane = tid & 63, wave = tid >> 6;
    const int l15 = lane & 15, l4 = lane >> 4;
    const int n0 = wave * 32;
    const int nb0 = blockIdx.x * 64;
    bf16x8 bw[2][4];
#pragma unroll
    for (int n = 0; n < 2; n++)
#pragma unroll
        for (int ks = 0; ks < 4; ks++)
            bw[n][ks] = *(const bf16x8*)&lwt[(n0 + n * 16 + l15) * 128 + ks * 32 + l4 * 8];
#pragma unroll
    for (int m = 0; m < 4; m++) {
        f32x4 acc0 = {0.f, 0.f, 0.f, 0.f}, acc1 = {0.f, 0.f, 0.f, 0.f};
        int arow = nb0 + m * 16 + l15;
        const float* ap = &vb[(size_t)(arow < N_ ? arow : 0) * HH];
#pragma unroll
        for (int ks = 0; ks < 4; ks++) {
            float4 x0 = *(const float4*)&ap[ks * 32 + l4 * 8];
            float4 x1 = *(const float4*)&ap[ks * 32 + l4 * 8 + 4];
            bf16x8 a = {f2bf(x0.x), f2bf(x0.y), f2bf(x0.z), f2bf(x0.w),
                        f2bf(x1.x), f2bf(x1.y), f2bf(x1.z), f2bf(x1.w)};
            acc0 = __builtin_amdgcn_mfma_f32_16x16x32_bf16(a, bw[0][ks], acc0, 0, 0, 0);
            acc1 = __builtin_amdgcn_mfma_f32_16x16x32_bf16(a, bw[1][ks], acc1, 0, 0, 0);
        }
#pragma unroll
        for (int r = 0; r < 4; r++) {
            int gn = nb0 + m * 16 + l4 * 4 + r;
            if (gn < N_) {
                out[(size_t)gn * FF + n0 + l15] = (unsigned short)f2bf(acc0[r]);
                out[(size_t)gn * FF + n0 + 16 + l15] = (unsigned short)f2bf(acc1[r]);
            }
        }
    }
}

// =========== fused layer kernel: block owns 32 nodes + their CSR edges ===========
// LDS: poolA(h1/wf/t2) 17.4K + poolB(vp/t1) 16.9K + agg 16.9K + idx 0.5K = 50.5 KB
__global__ __launch_bounds__(256, 3) void layer_kernel(
    const float* __restrict__ sdist, const float* __restrict__ sCb,
    const unsigned short* __restrict__ vin, const int* __restrict__ srow,
    const int* __restrict__ scol, const int* __restrict__ off_start,
    const int* __restrict__ off_end,
    const short* __restrict__ w1t, const float* __restrict__ b1,
    const short* __restrict__ w2t, const float* __restrict__ b2,
    const short* __restrict__ u1t, const float* __restrict__ ub1,
    const short* __restrict__ u2t, const float* __restrict__ ub2,
    float* __restrict__ vb, const short* __restrict__ lwt_next,
    unsigned short* __restrict__ vout, int N_) {
    __shared__ __align__(16) short poolA[64 * 136];   // h1 | wf | t2
    __shared__ __align__(16) short poolB[64 * 132];   // vp | t1
    __shared__ __align__(16) float agg_s[NPB * 132];
    __shared__ int srow_s[64], scol_s[64];
    short* h1_s = poolA;
    unsigned short* wf_s = (unsigned short*)poolA;
    unsigned short* vp_s = (unsigned short*)poolB;
    short* t1_s = poolB;
    short* t2_s = poolA;

    const int tid = threadIdx.x;
    const int lane = tid & 63, wave = tid >> 6;
    const int l15 = lane & 15, l4 = lane >> 4;
    const int n0w = wave * 32;
    const int nb0 = blockIdx.x * NPB;

    // edge-filter weight fragments (resident all kernel)
    bf16x8 bw1[2][2], bw2[2][4];
    float bias1[2], bias2[2];
#pragma unroll
    for (int n = 0; n < 2; n++) {
        const int fo = n0w + n * 16 + l15;
        bias1[n] = b1[fo];
        bias2[n] = b2[fo];
#pragma unroll
        for (int ks = 0; ks < 2; ks++)
            bw1[n][ks] = *(const bf16x8*)&w1t[fo * 64 + ks * 32 + l4 * 8];
#pragma unroll
        for (int ks = 0; ks < 4; ks++)
            bw2[n][ks] = *(const bf16x8*)&w2t[fo * 128 + ks * 32 + l4 * 8];
    }

    for (int i = tid; i < NPB * 132; i += 256) agg_s[i] = 0.f;

    const int estart = off_start[nb0];
    int lastn = nb0 + NPB - 1; if (lastn >= N_) lastn = N_ - 1;
    const int eend = off_end[lastn];
    const int cnt = eend - estart;
    const int nt = (cnt + ET - 1) / ET;

    const float STEP = 5.0f / 49.0f;
    const float COEFF = -0.5f / (STEP * STEP);

    for (int tt = 0; tt < nt; tt++) {
        const int te0 = estart + tt * ET;
        if (tid < 64) {
            int ge = te0 + tid; if (ge >= eend) ge = eend - 1;
            srow_s[tid] = srow[ge];
            scol_s[tid] = scol[ge] - nb0;   // local node idx 0..31
        }
        __syncthreads();

        // T14: issue gather early (16 independent 256B row reads per wave)
        unsigned g[16];
#pragma unroll
        for (int i = 0; i < 16; i++) {
            int e = wave * 16 + i;
            g[i] = *(const unsigned*)&vin[(size_t)srow_s[e] * FF + 2 * lane];
        }

        // demb in regs -> GEMM1 -> h1
#pragma unroll
        for (int m = 0; m < 4; m++) {
            int ge = te0 + m * 16 + l15; if (ge >= eend) ge = eend - 1;
            float d = sdist[ge];
            bf16x8 a0, a1;
#pragma unroll
            for (int j = 0; j < 8; j++) {
                int g0 = l4 * 8 + j;
                float x0 = fmaf((float)g0, -STEP, d);
                a0[j] = f2bf(__expf(COEFF * x0 * x0));
                int g1 = 32 + l4 * 8 + j;
                float x1 = fmaf((float)g1, -STEP, d);
                a1[j] = (g1 < GG) ? f2bf(__expf(COEFF * x1 * x1)) : (short)0;
            }
#pragma unroll
            for (int n = 0; n < 2; n++) {
                f32x4 acc = {bias1[n], bias1[n], bias1[n], bias1[n]};
                acc = __builtin_amdgcn_mfma_f32_16x16x32_bf16(a0, bw1[n][0], acc, 0, 0, 0);
                acc = __builtin_amdgcn_mfma_f32_16x16x32_bf16(a1, bw1[n][1], acc, 0, 0, 0);
                const int f = n0w + n * 16 + l15;
#pragma unroll
                for (int r = 0; r < 4; r++)
                    h1_s[(m * 16 + l4 * 4 + r) * 136 + f] = f2bf(ssp(acc[r]));
            }
        }
        __syncthreads();

        // GEMM2 into registers
        f32x4 accA[4], accB[4];
#pragma unroll
        for (int m = 0; m < 4; m++) {
            accA[m] = {bias2[0], bias2[0], bias2[0], bias2[0]};
            accB[m] = {bias2[1], bias2[1], bias2[1], bias2[1]};
#pragma unroll
            for (int ks = 0; ks < 4; ks++) {
                bf16x8 a = *(const bf16x8*)&h1_s[(m * 16 + l15) * 136 + ks * 32 + l4 * 8];
                accA[m] = __builtin_amdgcn_mfma_f32_16x16x32_bf16(a, bw2[0][ks], accA[m], 0, 0, 0);
                accB[m] = __builtin_amdgcn_mfma_f32_16x16x32_bf16(a, bw2[1][ks], accB[m], 0, 0, 0);
            }
        }
        __syncthreads();  // h1 reads done; wf may alias

        // wf = Wf * C (bf16, 0 for padded edges) + late write of gathered vp
#pragma unroll
        for (int m = 0; m < 4; m++) {
#pragma unroll
            for (int r = 0; r < 4; r++) {
                int er = m * 16 + l4 * 4 + r;
                int ge = te0 + er;
                float cb = (ge < eend) ? sCb[ge] : 0.f;
                wf_s[er * 132 + n0w + l15] = (unsigned short)f2bf(accA[m][r] * cb);
                wf_s[er * 132 + n0w + 16 + l15] = (unsigned short)f2bf(accB[m][r] * cb);
            }
        }
#pragma unroll
        for (int i = 0; i < 16; i++) {
            int e = wave * 16 + i;
            *(unsigned*)&vp_s[e * 132 + 2 * lane] = g[i];
        }
        __syncthreads();

        // walk: wave w handles edges [16w,16w+16), lane = feature-dword; LDS only
        {
            const int base = wave * 16;
            float a0 = 0.f, a1 = 0.f;
            int cur = scol_s[base];
#pragma unroll
            for (int i = 0; i < 16; i++) {
                int e = base + i;
                int c_ = scol_s[e];
                unsigned wp = *(const unsigned*)&wf_s[e * 132 + 2 * lane];
                unsigned vp = *(const unsigned*)&vp_s[e * 132 + 2 * lane];
                if (c_ != cur) {   // wave-uniform
                    atomicAdd(&agg_s[cur * 132 + 2 * lane], a0);
                    atomicAdd(&agg_s[cur * 132 + 2 * lane + 1], a1);
                    a0 = 0.f; a1 = 0.f; cur = c_;
                }
                a0 = fmaf(bf2f_lo(wp), bf2f_lo(vp), a0);
                a1 = fmaf(bf2f_hi(wp), bf2f_hi(vp), a1);
            }
            atomicAdd(&agg_s[cur * 132 + 2 * lane], a0);
            atomicAdd(&agg_s[cur * 132 + 2 * lane + 1], a1);
        }
        __syncthreads();
    }

    // ---------------- node MLP from agg_s ----------------
    // GEMM1: t1 = ssp(agg_s @ u1 + ub1)
    {
        bf16x8 bw[2][4];
        float bias[2];
#pragma unroll
        for (int n = 0; n < 2; n++) {
            bias[n] = ub1[n0w + n * 16 + l15];
#pragma unroll
            for (int ks = 0; ks < 4; ks++)
                bw[n][ks] = *(const bf16x8*)&u1t[(n0w + n * 16 + l15) * 128 + ks * 32 + l4 * 8];
        }
#pragma unroll
        for (int m = 0; m < 2; m++) {
            const float* ap = &agg_s[(m * 16 + l15) * 132];
            f32x4 acc0 = {bias[0], bias[0], bias[0], bias[0]};
            f32x4 acc1 = {bias[1], bias[1], bias[1], bias[1]};
#pragma unroll
            for (int ks = 0; ks < 4; ks++) {
                float4 x0 = *(const float4*)&ap[ks * 32 + l4 * 8];
                float4 x1 = *(const float4*)&ap[ks * 32 + l4 * 8 + 4];
                bf16x8 a = {f2bf(x0.x), f2bf(x0.y), f2bf(x0.z), f2bf(x0.w),
                            f2bf(x1.x), f2bf(x1.y), f2bf(x1.z), f2bf(x1.w)};
                acc0 = __builtin_amdgcn_mfma_f32_16x16x32_bf16(a, bw[0][ks], acc0, 0, 0, 0);
                acc1 = __builtin_amdgcn_mfma_f32_16x16x32_bf16(a, bw[1][ks], acc1, 0, 0, 0);
            }
#pragma unroll
            for (int r = 0; r < 4; r++) {
                int er = m * 16 + l4 * 4 + r;
                t1_s[er * 136 + n0w + l15] = f2bf(ssp(acc0[r]));
                t1_s[er * 136 + n0w + 16 + l15] = f2bf(ssp(acc1[r]));
            }
        }
    }
    __syncthreads();

    // GEMM2: v_new = v + (t1 @ u2 + ub2); write vb + t2_s
    {
        bf16x8 bw[2][4];
        float bias[2];
#pragma unroll
        for (int n = 0; n < 2; n++) {
            bias[n] = ub2[n0w + n * 16 + l15];
#pragma unroll
            for (int ks = 0; ks < 4; ks++)
                bw[n][ks] = *(const bf16x8*)&u2t[(n0w + n * 16 + l15) * 128 + ks * 32 + l4 * 8];
        }
#pragma unroll
        for (int m = 0; m < 2; m++) {
            f32x4 acc0 = {bias[0], bias[0], bias[0], bias[0]};
            f32x4 acc1 = {bias[1], bias[1], bias[1], bias[1]};
#pragma unroll
            for (int ks = 0; ks < 4; ks++) {
                bf16x8 a = *(const bf16x8*)&t1_s[(m * 16 + l15) * 136 + ks * 32 + l4 * 8];
                acc0 = __builtin_amdgcn_mfma_f32_16x16x32_bf16(a, bw[0][ks], acc0, 0, 0, 0);
                acc1 = __builtin_amdgcn_mfma_f32_16x16x32_bf16(a, bw[1][ks], acc1, 0, 0, 0);
            }
#pragma unroll
            for (int r = 0; r < 4; r++) {
                int er = m * 16 + l4 * 4 + r;
                int gn = nb0 + er;
                if (gn < N_) {
                    size_t i0 = (size_t)gn * HH + n0w + l15;
                    size_t i1 = (size_t)gn * HH + n0w + 16 + l15;
                    float v0 = vb[i0] + acc0[r];
                    float v1 = vb[i1] + acc1[r];
                    vb[i0] = v0;
                    vb[i1] = v1;
                    t2_s[er * 136 + n0w + l15] = f2bf(v0);
                    t2_s[er * 136 + n0w + 16 + l15] = f2bf(v1);
                } else {
                    t2_s[er * 136 + n0w + l15] = 0;
                    t2_s[er * 136 + n0w + 16 + l15] = 0;
                }
            }
        }
    }
    __syncthreads();

    // GEMM3: vout = v_new @ lin_w[l+1] (bf16)
    if (lwt_next) {
        bf16x8 bw[2][4];
#pragma unroll
        for (int n = 0; n < 2; n++)
#pragma unroll
            for (int ks = 0; ks < 4; ks++)
                bw[n][ks] = *(const bf16x8*)&lwt_next[(n0w + n * 16 + l15) * 128 + ks * 32 + l4 * 8];
#pragma unroll
        for (int m = 0; m < 2; m++) {
            f32x4 acc0 = {0.f, 0.f, 0.f, 0.f}, acc1 = {0.f, 0.f, 0.f, 0.f};
#pragma unroll
            for (int ks = 0; ks < 4; ks++) {
                bf16x8 a = *(const bf16x8*)&t2_s[(m * 16 + l15) * 136 + ks * 32 + l4 * 8];
                acc0 = __builtin_amdgcn_mfma_f32_16x16x32_bf16(a, bw[0][ks], acc0, 0, 0, 0);
                acc1 = __builtin_amdgcn_mfma_f32_16x16x32_bf16(a, bw[1][ks], acc1, 0, 0, 0);
            }
#pragma unroll
            for (int r = 0; r < 4; r++) {
                int gn = nb0 + m * 16 + l4 * 4 + r;
                if (gn < N_) {
                    vout[(size_t)gn * FF + n0w + l15] = (unsigned short)f2bf(acc0[r]);
                    vout[(size_t)gn * FF + n0w + 16 + l15] = (unsigned short)f2bf(acc1[r]);
                }
            }
        }
    }
}

extern "C" void kernel_launch(void* const* d_in, const int* in_sizes, int n_in,
                              void* d_out, int out_size, void* d_ws, size_t ws_size,
                              hipStream_t stream) {
    const float* v = (const float*)d_in[0];
    const float* pos = (const float*)d_in[1];
    const float* offs = (const float*)d_in[2];
    const int* edges = (const int*)d_in[3];
    const float* lin_w = (const float*)d_in[4];
    const float* w1 = (const float*)d_in[5];
    const float* b1 = (const float*)d_in[6];
    const float* w2 = (const float*)d_in[7];
    const float* b2 = (const float*)d_in[8];
    const float* u1 = (const float*)d_in[9];
    const float* ub1 = (const float*)d_in[10];
    const float* u2 = (const float*)d_in[11];
    const float* ub2 = (const float*)d_in[12];

    const int N = in_sizes[0] / HH;
    const int E = in_sizes[3] / 2;
    const int* row = edges;
    const int* col = edges + E;

    char* base = (char*)d_ws;
    int* counts = (int*)base;    base += (size_t)N * 4;
    int* woff = (int*)base;      base += (size_t)N * 4;
    int* offsets = (int*)base;   base += (size_t)N * 4;
    int* srow = (int*)base;      base += (size_t)E * 4;
    int* scol = (int*)base;      base += (size_t)E * 4;
    float* sdist = (float*)base; base += (size_t)E * 4;
    float* sCb = (float*)base;   base += (size_t)E * 4;
    float* vbuf = (float*)base;  base += (size_t)N * HH * 4;
    unsigned short* vprojA = (unsigned short*)base; base += (size_t)N * FF * 2;
    unsigned short* vprojB = (unsigned short*)base; base += (size_t)N * FF * 2;
    short* w1t = (short*)base;   base += (size_t)NLAYERS * FF * 64 * 2;
    short* w2t = (short*)base;   base += (size_t)NLAYERS * FF * FF * 2;
    short* u1t = (short*)base;   base += (size_t)NLAYERS * FF * FF * 2;
    short* u2t = (short*)base;   base += (size_t)NLAYERS * FF * FF * 2;
    short* lin_wt = (short*)base;

    const int EB = (E + 255) / 256;
    const int NB64 = (N + 63) / 64;
    const int NBn = (N + NPB - 1) / NPB;

    hipMemsetAsync(counts, 0, (size_t)N * 4, stream);
    hist_kernel<<<EB, 256, 0, stream>>>(col, counts, E);
    scan_kernel<<<1, 1024, 0, stream>>>(counts, offsets, woff, N);
    scatter_kernel<<<EB, 256, 0, stream>>>(pos, offs, row, col, woff, srow, scol,
                                           sdist, sCb, E);
    prep_kernel<<<(NLAYERS * FF * FF + 255) / 256, 256, 0, stream>>>(
        w1, w2, u1, u2, lin_w, w1t, w2t, u1t, u2t, lin_wt);
    hipMemcpyAsync(vbuf, v, (size_t)N * HH * sizeof(float),
                   hipMemcpyDeviceToDevice, stream);
    vproj0_kernel<<<NB64, 256, 0, stream>>>(v, lin_wt, vprojA, N);

    for (int l = 0; l < NLAYERS; l++) {
        unsigned short* vin = (l & 1) ? vprojB : vprojA;
        unsigned short* vout = (l & 1) ? vprojA : vprojB;
        layer_kernel<<<NBn, 256, 0, stream>>>(
            sdist, sCb, vin, srow, scol, offsets, woff,
            w1t + (size_t)l * FF * 64, b1 + (size_t)l * FF,
            w2t + (size_t)l * FF * FF, b2 + (size_t)l * FF,
            u1t + (size_t)l * FF * FF, ub1 + (size_t)l * HH,
            u2t + (size_t)l * FF * FF, ub2 + (size_t)l * HH, vbuf,
            (l + 1 < NLAYERS) ? (lin_wt + (size_t)(l + 1) * FF * FF) : nullptr,
            vout, N);
    }
    hipMemcpyAsync(d_out, vbuf, (size_t)N * HH * sizeof(float),
                   hipMemcpyDeviceToDevice, stream);
}

// Round 10
// 535.680 us; speedup vs baseline: 1.9710x; 1.9420x over previous
//
#include <hip/hip_runtime.h>
#include <hip/hip_bf16.h>
#include <math.h>

#define HH 128
#define FF 128
#define GG 50
#define NLAYERS 6
#define NPB 32
#define TAB 4096
#define TABH 0.001953125f   // 8.0 / 4096
#define TABINVH 512.0f

typedef __attribute__((ext_vector_type(8))) short bf16x8;
typedef __attribute__((ext_vector_type(4))) float f32x4;

static __device__ __forceinline__ float ssp(float x) {
    return fmaxf(x, 0.f) + __logf(1.f + __expf(-fabsf(x))) - 0.6931471805599453f;
}

static __device__ __forceinline__ short f2bf(float x) {
    union { float f; unsigned u; } c; c.f = x;
    unsigned r = (c.u + 0x7FFF + ((c.u >> 16) & 1)) >> 16;
    return (short)r;
}

static __device__ __forceinline__ float bf2f_lo(unsigned p) {
    union { unsigned u; float f; } c; c.u = p << 16; return c.f;
}
static __device__ __forceinline__ float bf2f_hi(unsigned p) {
    union { unsigned u; float f; } c; c.u = p & 0xFFFF0000u; return c.f;
}

// ---------------- sort pipeline: hist -> scan -> scatter ----------------
__global__ void hist_kernel(const int* __restrict__ col, int* __restrict__ counts, int E_) {
    int e = blockIdx.x * 256 + threadIdx.x;
    if (e < E_) atomicAdd(&counts[col[e]], 1);
}

__global__ __launch_bounds__(1024) void scan_kernel(const int* __restrict__ counts,
                                                    int* __restrict__ offsets,
                                                    int* __restrict__ woff, int N_) {
    __shared__ int wsum[16];
    __shared__ int carry_s;
    const int tid = threadIdx.x;
    const int lane = tid & 63, wid = tid >> 6;
    if (tid == 0) carry_s = 0;
    __syncthreads();
    for (int base = 0; base < N_; base += 1024) {
        int i = base + tid;
        int val = (i < N_) ? counts[i] : 0;
        int x = val;
#pragma unroll
        for (int d = 1; d < 64; d <<= 1) {
            int t = __shfl_up(x, d, 64);
            if (lane >= d) x += t;
        }
        if (lane == 63) wsum[wid] = x;
        int carry = carry_s;
        __syncthreads();
        if (wid == 0) {
            int s = (lane < 16) ? wsum[lane] : 0;
#pragma unroll
            for (int d = 1; d < 16; d <<= 1) {
                int t = __shfl_up(s, d, 64);
                if (lane >= d) s += t;
            }
            if (lane < 16) wsum[lane] = s;
            if (lane == 15) carry_s = carry + s;
        }
        __syncthreads();
        int woffset = (wid > 0) ? wsum[wid - 1] : 0;
        if (i < N_) {
            int ex = carry + woffset + x - val;  // exclusive
            offsets[i] = ex;
            woff[i] = ex;
        }
        __syncthreads();
    }
}

__global__ void scatter_kernel(const float* __restrict__ pos,
                               const float* __restrict__ offs,
                               const int* __restrict__ row,
                               const int* __restrict__ col,
                               int* __restrict__ woff,
                               int* __restrict__ srow,
                               float* __restrict__ sdist, int E_) {
    int e = blockIdx.x * 256 + threadIdx.x;
    if (e >= E_) return;
    int r = row[e], c = col[e];
    float dx = pos[c * 3 + 0] + offs[e * 3 + 0] - pos[r * 3 + 0];
    float dy = pos[c * 3 + 1] + offs[e * 3 + 1] - pos[r * 3 + 1];
    float dz = pos[c * 3 + 2] + offs[e * 3 + 2] - pos[r * 3 + 2];
    float d = sqrtf(dx * dx + dy * dy + dz * dz);
    int p = atomicAdd(&woff[c], 1);
    srow[p] = r;
    sdist[p] = d;
}

// ------------- prep: transpose + bf16 all weights (all layers) -------------
__global__ __launch_bounds__(256) void prep_kernel(
    const float* __restrict__ w1, const float* __restrict__ w2,
    const float* __restrict__ u1, const float* __restrict__ u2,
    const float* __restrict__ lin_w,
    short* __restrict__ w1t, short* __restrict__ w2t,
    short* __restrict__ u1t, short* __restrict__ u2t, short* __restrict__ lin_wt) {
    int idx = blockIdx.x * 256 + threadIdx.x;
    if (idx < NLAYERS * FF * FF) {
        int l = idx >> 14, r = idx & 16383, a = r >> 7, b = r & 127;
        size_t src = (size_t)l * FF * FF + (size_t)b * FF + a;  // [l][b][a]
        w2t[idx] = f2bf(w2[src]);
        u1t[idx] = f2bf(u1[src]);
        u2t[idx] = f2bf(u2[src]);
        lin_wt[idx] = f2bf(lin_w[src]);
    }
    if (idx < NLAYERS * FF * 64) {
        int l = idx >> 13, r = idx & 8191, fo = r >> 6, g = r & 63;
        w1t[idx] = f2bf(g < GG ? w1[((size_t)l * GG + g) * FF + fo] : 0.f);
    }
}

// ---------------- vproj0 = v(f32) @ lin_w[0]  via MFMA, bf16 out ----------------
__global__ __launch_bounds__(256) void vproj0_kernel(const float* __restrict__ vb,
                                                     const short* __restrict__ lwt,
                                                     unsigned short* __restrict__ out,
                                                     int N_) {
    const int tid = threadIdx.x;
    const int lane = tid & 63, wave = tid >> 6;
    const int l15 = lane & 15, l4 = lane >> 4;
    const int n0 = wave * 32;
    const int nb0 = blockIdx.x * 64;
    bf16x8 bw[2][4];
#pragma unroll
    for (int n = 0; n < 2; n++)
#pragma unroll
        for (int ks = 0; ks < 4; ks++)
            bw[n][ks] = *(const bf16x8*)&lwt[(n0 + n * 16 + l15) * 128 + ks * 32 + l4 * 8];
#pragma unroll
    for (int m = 0; m < 4; m++) {
        f32x4 acc0 = {0.f, 0.f, 0.f, 0.f}, acc1 = {0.f, 0.f, 0.f, 0.f};
        int arow = nb0 + m * 16 + l15;
        const float* ap = &vb[(size_t)(arow < N_ ? arow : 0) * HH];
#pragma unroll
        for (int ks = 0; ks < 4; ks++) {
            float4 x0 = *(const float4*)&ap[ks * 32 + l4 * 8];
            float4 x1 = *(const float4*)&ap[ks * 32 + l4 * 8 + 4];
            bf16x8 a = {f2bf(x0.x), f2bf(x0.y), f2bf(x0.z), f2bf(x0.w),
                        f2bf(x1.x), f2bf(x1.y), f2bf(x1.z), f2bf(x1.w)};
            acc0 = __builtin_amdgcn_mfma_f32_16x16x32_bf16(a, bw[0][ks], acc0, 0, 0, 0);
            acc1 = __builtin_amdgcn_mfma_f32_16x16x32_bf16(a, bw[1][ks], acc1, 0, 0, 0);
        }
#pragma unroll
        for (int r = 0; r < 4; r++) {
            int gn = nb0 + m * 16 + l4 * 4 + r;
            if (gn < N_) {
                out[(size_t)gn * FF + n0 + l15] = (unsigned short)f2bf(acc0[r]);
                out[(size_t)gn * FF + n0 + 16 + l15] = (unsigned short)f2bf(acc1[r]);
            }
        }
    }
}

// -------- table build: tab[l][i][f] = ((ssp(demb(ih)@w1+b1)@w2)+b2)*C(ih), bf16 ----
__global__ __launch_bounds__(256) void tab_kernel(
    const short* __restrict__ w1t, const float* __restrict__ b1,
    const short* __restrict__ w2t, const float* __restrict__ b2,
    unsigned short* __restrict__ tab) {
    __shared__ __align__(16) short h1_s[64 * 136];
    const int tid = threadIdx.x;
    const int lane = tid & 63, wave = tid >> 6;
    const int l15 = lane & 15, l4 = lane >> 4;
    const int n0w = wave * 32;
    const int l = blockIdx.x / (TAB / 64);
    const int tb0 = (blockIdx.x % (TAB / 64)) * 64;
    const short* w1l = w1t + (size_t)l * FF * 64;
    const short* w2l = w2t + (size_t)l * FF * FF;
    unsigned short* tabl = tab + (size_t)l * TAB * FF;

    bf16x8 bw1[2][2], bw2[2][4];
    float bias1[2], bias2[2];
#pragma unroll
    for (int n = 0; n < 2; n++) {
        const int fo = n0w + n * 16 + l15;
        bias1[n] = b1[(size_t)l * FF + fo];
        bias2[n] = b2[(size_t)l * FF + fo];
#pragma unroll
        for (int ks = 0; ks < 2; ks++)
            bw1[n][ks] = *(const bf16x8*)&w1l[fo * 64 + ks * 32 + l4 * 8];
#pragma unroll
        for (int ks = 0; ks < 4; ks++)
            bw2[n][ks] = *(const bf16x8*)&w2l[fo * 128 + ks * 32 + l4 * 8];
    }

    const float STEP = 5.0f / 49.0f;
    const float COEFF = -0.5f / (STEP * STEP);
#pragma unroll
    for (int m = 0; m < 4; m++) {
        float d = (float)(tb0 + m * 16 + l15) * TABH;
        bf16x8 a0, a1;
#pragma unroll
        for (int j = 0; j < 8; j++) {
            int g0 = l4 * 8 + j;
            float x0 = fmaf((float)g0, -STEP, d);
            a0[j] = f2bf(__expf(COEFF * x0 * x0));
            int g1 = 32 + l4 * 8 + j;
            float x1 = fmaf((float)g1, -STEP, d);
            a1[j] = (g1 < GG) ? f2bf(__expf(COEFF * x1 * x1)) : (short)0;
        }
#pragma unroll
        for (int n = 0; n < 2; n++) {
            f32x4 acc = {bias1[n], bias1[n], bias1[n], bias1[n]};
            acc = __builtin_amdgcn_mfma_f32_16x16x32_bf16(a0, bw1[n][0], acc, 0, 0, 0);
            acc = __builtin_amdgcn_mfma_f32_16x16x32_bf16(a1, bw1[n][1], acc, 0, 0, 0);
            const int f = n0w + n * 16 + l15;
#pragma unroll
            for (int r = 0; r < 4; r++)
                h1_s[(m * 16 + l4 * 4 + r) * 136 + f] = f2bf(ssp(acc[r]));
        }
    }
    __syncthreads();

#pragma unroll
    for (int m = 0; m < 4; m++) {
        f32x4 accA = {bias2[0], bias2[0], bias2[0], bias2[0]};
        f32x4 accB = {bias2[1], bias2[1], bias2[1], bias2[1]};
#pragma unroll
        for (int ks = 0; ks < 4; ks++) {
            bf16x8 a = *(const bf16x8*)&h1_s[(m * 16 + l15) * 136 + ks * 32 + l4 * 8];
            accA = __builtin_amdgcn_mfma_f32_16x16x32_bf16(a, bw2[0][ks], accA, 0, 0, 0);
            accB = __builtin_amdgcn_mfma_f32_16x16x32_bf16(a, bw2[1][ks], accB, 0, 0, 0);
        }
#pragma unroll
        for (int r = 0; r < 4; r++) {
            int entry = tb0 + m * 16 + l4 * 4 + r;
            float de = (float)entry * TABH;
            float C = 0.5f * (cosf(de * 0.6283185307179586f) + 1.0f);
            tabl[(size_t)entry * FF + n0w + l15] = (unsigned short)f2bf(accA[r] * C);
            tabl[(size_t)entry * FF + n0w + 16 + l15] = (unsigned short)f2bf(accB[r] * C);
        }
    }
}

// ===== fused layer: per-wave node-owned CSR aggregation (table lerp) + MLP =====
// LDS = agg(16.9K) + t1(8.7K); t2 aliases agg. ~25.6 KB -> 6 blk/CU.
__global__ __launch_bounds__(256) void layer_kernel(
    const float* __restrict__ sdist, const int* __restrict__ srow,
    const int* __restrict__ off_start, const int* __restrict__ off_end,
    const unsigned short* __restrict__ tab, const unsigned short* __restrict__ vin,
    const short* __restrict__ u1t, const float* __restrict__ ub1,
    const short* __restrict__ u2t, const float* __restrict__ ub2,
    float* __restrict__ vb, const short* __restrict__ lwt_next,
    unsigned short* __restrict__ vout, int N_) {
    __shared__ __align__(16) float agg_s[NPB * 132];
    __shared__ __align__(16) short t1_s[NPB * 136];
    short* t2_s = (short*)agg_s;   // alias: agg dead after MLP GEMM1

    const int tid = threadIdx.x;
    const int lane = tid & 63, wave = tid >> 6;
    const int l15 = lane & 15, l4 = lane >> 4;
    const int n0w = wave * 32;
    const int nb0 = blockIdx.x * NPB;

    // ---- edge aggregation: wave w owns nodes [8w, 8w+8); register acc; no atomics
    for (int s = 0; s < 8; s++) {
        const int nl = wave * 8 + s;
        const int n = nb0 + nl;
        float acc0 = 0.f, acc1 = 0.f;
        if (n < N_) {
            const int e0 = off_start[n], e1 = off_end[n];
            for (int base = e0; base < e1; base += 64) {
                const int cnt = min(64, e1 - base);
                int eidx = base + lane;
                if (eidx >= e1) eidx = e1 - 1;
                const float md = sdist[eidx];
                const int mr = srow[eidx];
#pragma unroll 4
                for (int i = 0; i < cnt; i++) {
                    const float d = __shfl(md, i);
                    const int r = __shfl(mr, i);
                    float x = d * TABINVH;
                    int ix = (int)x;
                    ix = (ix < TAB - 2) ? ix : (TAB - 2);
                    const float fr = x - (float)ix;
                    const unsigned ta = *(const unsigned*)&tab[(size_t)ix * FF + 2 * lane];
                    const unsigned tb = *(const unsigned*)&tab[(size_t)(ix + 1) * FF + 2 * lane];
                    const unsigned vp = *(const unsigned*)&vin[(size_t)r * FF + 2 * lane];
                    const float w0 = fmaf(fr, bf2f_lo(tb) - bf2f_lo(ta), bf2f_lo(ta));
                    const float w1 = fmaf(fr, bf2f_hi(tb) - bf2f_hi(ta), bf2f_hi(ta));
                    acc0 = fmaf(w0, bf2f_lo(vp), acc0);
                    acc1 = fmaf(w1, bf2f_hi(vp), acc1);
                }
            }
        }
        agg_s[nl * 132 + 2 * lane] = acc0;
        agg_s[nl * 132 + 2 * lane + 1] = acc1;
    }
    __syncthreads();

    // ---- MLP GEMM1: t1 = ssp(agg @ u1 + ub1)
    {
        bf16x8 bw[2][4];
        float bias[2];
#pragma unroll
        for (int n = 0; n < 2; n++) {
            bias[n] = ub1[n0w + n * 16 + l15];
#pragma unroll
            for (int ks = 0; ks < 4; ks++)
                bw[n][ks] = *(const bf16x8*)&u1t[(n0w + n * 16 + l15) * 128 + ks * 32 + l4 * 8];
        }
#pragma unroll
        for (int m = 0; m < 2; m++) {
            const float* ap = &agg_s[(m * 16 + l15) * 132];
            f32x4 acc0 = {bias[0], bias[0], bias[0], bias[0]};
            f32x4 acc1 = {bias[1], bias[1], bias[1], bias[1]};
#pragma unroll
            for (int ks = 0; ks < 4; ks++) {
                float4 x0 = *(const float4*)&ap[ks * 32 + l4 * 8];
                float4 x1 = *(const float4*)&ap[ks * 32 + l4 * 8 + 4];
                bf16x8 a = {f2bf(x0.x), f2bf(x0.y), f2bf(x0.z), f2bf(x0.w),
                            f2bf(x1.x), f2bf(x1.y), f2bf(x1.z), f2bf(x1.w)};
                acc0 = __builtin_amdgcn_mfma_f32_16x16x32_bf16(a, bw[0][ks], acc0, 0, 0, 0);
                acc1 = __builtin_amdgcn_mfma_f32_16x16x32_bf16(a, bw[1][ks], acc1, 0, 0, 0);
            }
#pragma unroll
            for (int r = 0; r < 4; r++) {
                int er = m * 16 + l4 * 4 + r;
                t1_s[er * 136 + n0w + l15] = f2bf(ssp(acc0[r]));
                t1_s[er * 136 + n0w + 16 + l15] = f2bf(ssp(acc1[r]));
            }
        }
    }
    __syncthreads();

    // ---- MLP GEMM2: v_new = v + (t1 @ u2 + ub2); write vb + t2_s (aliases agg)
    {
        bf16x8 bw[2][4];
        float bias[2];
#pragma unroll
        for (int n = 0; n < 2; n++) {
            bias[n] = ub2[n0w + n * 16 + l15];
#pragma unroll
            for (int ks = 0; ks < 4; ks++)
                bw[n][ks] = *(const bf16x8*)&u2t[(n0w + n * 16 + l15) * 128 + ks * 32 + l4 * 8];
        }
#pragma unroll
        for (int m = 0; m < 2; m++) {
            f32x4 acc0 = {bias[0], bias[0], bias[0], bias[0]};
            f32x4 acc1 = {bias[1], bias[1], bias[1], bias[1]};
#pragma unroll
            for (int ks = 0; ks < 4; ks++) {
                bf16x8 a = *(const bf16x8*)&t1_s[(m * 16 + l15) * 136 + ks * 32 + l4 * 8];
                acc0 = __builtin_amdgcn_mfma_f32_16x16x32_bf16(a, bw[0][ks], acc0, 0, 0, 0);
                acc1 = __builtin_amdgcn_mfma_f32_16x16x32_bf16(a, bw[1][ks], acc1, 0, 0, 0);
            }
#pragma unroll
            for (int r = 0; r < 4; r++) {
                int er = m * 16 + l4 * 4 + r;
                int gn = nb0 + er;
                if (gn < N_) {
                    size_t i0 = (size_t)gn * HH + n0w + l15;
                    size_t i1 = (size_t)gn * HH + n0w + 16 + l15;
                    float v0 = vb[i0] + acc0[r];
                    float v1 = vb[i1] + acc1[r];
                    vb[i0] = v0;
                    vb[i1] = v1;
                    t2_s[er * 136 + n0w + l15] = f2bf(v0);
                    t2_s[er * 136 + n0w + 16 + l15] = f2bf(v1);
                } else {
                    t2_s[er * 136 + n0w + l15] = 0;
                    t2_s[er * 136 + n0w + 16 + l15] = 0;
                }
            }
        }
    }
    __syncthreads();

    // ---- MLP GEMM3: vout = v_new @ lin_w[l+1] (bf16)
    if (lwt_next) {
        bf16x8 bw[2][4];
#pragma unroll
        for (int n = 0; n < 2; n++)
#pragma unroll
            for (int ks = 0; ks < 4; ks++)
                bw[n][ks] = *(const bf16x8*)&lwt_next[(n0w + n * 16 + l15) * 128 + ks * 32 + l4 * 8];
#pragma unroll
        for (int m = 0; m < 2; m++) {
            f32x4 acc0 = {0.f, 0.f, 0.f, 0.f}, acc1 = {0.f, 0.f, 0.f, 0.f};
#pragma unroll
            for (int ks = 0; ks < 4; ks++) {
                bf16x8 a = *(const bf16x8*)&t2_s[(m * 16 + l15) * 136 + ks * 32 + l4 * 8];
                acc0 = __builtin_amdgcn_mfma_f32_16x16x32_bf16(a, bw[0][ks], acc0, 0, 0, 0);
                acc1 = __builtin_amdgcn_mfma_f32_16x16x32_bf16(a, bw[1][ks], acc1, 0, 0, 0);
            }
#pragma unroll
            for (int r = 0; r < 4; r++) {
                int gn = nb0 + m * 16 + l4 * 4 + r;
                if (gn < N_) {
                    vout[(size_t)gn * FF + n0w + l15] = (unsigned short)f2bf(acc0[r]);
                    vout[(size_t)gn * FF + n0w + 16 + l15] = (unsigned short)f2bf(acc1[r]);
                }
            }
        }
    }
}

extern "C" void kernel_launch(void* const* d_in, const int* in_sizes, int n_in,
                              void* d_out, int out_size, void* d_ws, size_t ws_size,
                              hipStream_t stream) {
    const float* v = (const float*)d_in[0];
    const float* pos = (const float*)d_in[1];
    const float* offs = (const float*)d_in[2];
    const int* edges = (const int*)d_in[3];
    const float* lin_w = (const float*)d_in[4];
    const float* w1 = (const float*)d_in[5];
    const float* b1 = (const float*)d_in[6];
    const float* w2 = (const float*)d_in[7];
    const float* b2 = (const float*)d_in[8];
    const float* u1 = (const float*)d_in[9];
    const float* ub1 = (const float*)d_in[10];
    const float* u2 = (const float*)d_in[11];
    const float* ub2 = (const float*)d_in[12];

    const int N = in_sizes[0] / HH;
    const int E = in_sizes[3] / 2;
    const int* row = edges;
    const int* col = edges + E;

    char* base = (char*)d_ws;
    int* counts = (int*)base;    base += (size_t)N * 4;
    int* woff = (int*)base;      base += (size_t)N * 4;
    int* offsets = (int*)base;   base += (size_t)N * 4;
    int* srow = (int*)base;      base += (size_t)E * 4;
    float* sdist = (float*)base; base += (size_t)E * 4;
    float* vbuf = (float*)base;  base += (size_t)N * HH * 4;
    unsigned short* vprojA = (unsigned short*)base; base += (size_t)N * FF * 2;
    unsigned short* vprojB = (unsigned short*)base; base += (size_t)N * FF * 2;
    short* w1t = (short*)base;   base += (size_t)NLAYERS * FF * 64 * 2;
    short* w2t = (short*)base;   base += (size_t)NLAYERS * FF * FF * 2;
    short* u1t = (short*)base;   base += (size_t)NLAYERS * FF * FF * 2;
    short* u2t = (short*)base;   base += (size_t)NLAYERS * FF * FF * 2;
    short* lin_wt = (short*)base; base += (size_t)NLAYERS * FF * FF * 2;
    unsigned short* tab = (unsigned short*)base;   // 6 * 4096 * 128 bf16 = 6.3 MB

    const int EB = (E + 255) / 256;
    const int NB64 = (N + 63) / 64;
    const int NBn = (N + NPB - 1) / NPB;

    hipMemsetAsync(counts, 0, (size_t)N * 4, stream);
    hist_kernel<<<EB, 256, 0, stream>>>(col, counts, E);
    scan_kernel<<<1, 1024, 0, stream>>>(counts, offsets, woff, N);
    scatter_kernel<<<EB, 256, 0, stream>>>(pos, offs, row, col, woff, srow, sdist, E);
    prep_kernel<<<(NLAYERS * FF * FF + 255) / 256, 256, 0, stream>>>(
        w1, w2, u1, u2, lin_w, w1t, w2t, u1t, u2t, lin_wt);
    tab_kernel<<<NLAYERS * (TAB / 64), 256, 0, stream>>>(w1t, b1, w2t, b2, tab);
    hipMemcpyAsync(vbuf, v, (size_t)N * HH * sizeof(float),
                   hipMemcpyDeviceToDevice, stream);
    vproj0_kernel<<<NB64, 256, 0, stream>>>(v, lin_wt, vprojA, N);

    for (int l = 0; l < NLAYERS; l++) {
        unsigned short* vin = (l & 1) ? vprojB : vprojA;
        unsigned short* vout = (l & 1) ? vprojA : vprojB;
        layer_kernel<<<NBn, 256, 0, stream>>>(
            sdist, srow, offsets, woff, tab + (size_t)l * TAB * FF, vin,
            u1t + (size_t)l * FF * FF, ub1 + (size_t)l * HH,
            u2t + (size_t)l * FF * FF, ub2 + (size_t)l * HH, vbuf,
            (l + 1 < NLAYERS) ? (lin_wt + (size_t)(l + 1) * FF * FF) : nullptr,
            vout, N);
    }
    hipMemcpyAsync(d_out, vbuf, (size_t)N * HH * sizeof(float),
                   hipMemcpyDeviceToDevice, stream);
}

// Round 11
// 426.892 us; speedup vs baseline: 2.4733x; 1.2548x over previous
//
#include <hip/hip_runtime.h>
#include <hip/hip_bf16.h>
#include <math.h>

#define HH 128
#define FF 128
#define GG 50
#define NLAYERS 6
#define NPB 32
#define TAB 4096
#define TABH 0.001953125f   // 8.0 / 4096
#define TABINVH 512.0f

typedef __attribute__((ext_vector_type(8))) short bf16x8;
typedef __attribute__((ext_vector_type(4))) float f32x4;

static __device__ __forceinline__ float ssp(float x) {
    return fmaxf(x, 0.f) + __logf(1.f + __expf(-fabsf(x))) - 0.6931471805599453f;
}

static __device__ __forceinline__ short f2bf(float x) {
    union { float f; unsigned u; } c; c.f = x;
    unsigned r = (c.u + 0x7FFF + ((c.u >> 16) & 1)) >> 16;
    return (short)r;
}

static __device__ __forceinline__ float bf2f_lo(unsigned p) {
    union { unsigned u; float f; } c; c.u = p << 16; return c.f;
}
static __device__ __forceinline__ float bf2f_hi(unsigned p) {
    union { unsigned u; float f; } c; c.u = p & 0xFFFF0000u; return c.f;
}

// ---------------- sort pipeline: hist -> scan -> scatter ----------------
__global__ void hist_kernel(const int* __restrict__ col, int* __restrict__ counts, int E_) {
    int e = blockIdx.x * 256 + threadIdx.x;
    if (e < E_) atomicAdd(&counts[col[e]], 1);
}

__global__ __launch_bounds__(1024) void scan_kernel(const int* __restrict__ counts,
                                                    int* __restrict__ offsets,
                                                    int* __restrict__ woff, int N_) {
    __shared__ int wsum[16];
    __shared__ int carry_s;
    const int tid = threadIdx.x;
    const int lane = tid & 63, wid = tid >> 6;
    if (tid == 0) carry_s = 0;
    __syncthreads();
    for (int base = 0; base < N_; base += 1024) {
        int i = base + tid;
        int val = (i < N_) ? counts[i] : 0;
        int x = val;
#pragma unroll
        for (int d = 1; d < 64; d <<= 1) {
            int t = __shfl_up(x, d, 64);
            if (lane >= d) x += t;
        }
        if (lane == 63) wsum[wid] = x;
        int carry = carry_s;
        __syncthreads();
        if (wid == 0) {
            int s = (lane < 16) ? wsum[lane] : 0;
#pragma unroll
            for (int d = 1; d < 16; d <<= 1) {
                int t = __shfl_up(s, d, 64);
                if (lane >= d) s += t;
            }
            if (lane < 16) wsum[lane] = s;
            if (lane == 15) carry_s = carry + s;
        }
        __syncthreads();
        int woffset = (wid > 0) ? wsum[wid - 1] : 0;
        if (i < N_) {
            int ex = carry + woffset + x - val;  // exclusive
            offsets[i] = ex;
            woff[i] = ex;
        }
        __syncthreads();
    }
}

__global__ void scatter_kernel(const float* __restrict__ pos,
                               const float* __restrict__ offs,
                               const int* __restrict__ row,
                               const int* __restrict__ col,
                               int* __restrict__ woff,
                               int* __restrict__ srow,
                               float* __restrict__ sdist, int E_) {
    int e = blockIdx.x * 256 + threadIdx.x;
    if (e >= E_) return;
    int r = row[e], c = col[e];
    float dx = pos[c * 3 + 0] + offs[e * 3 + 0] - pos[r * 3 + 0];
    float dy = pos[c * 3 + 1] + offs[e * 3 + 1] - pos[r * 3 + 1];
    float dz = pos[c * 3 + 2] + offs[e * 3 + 2] - pos[r * 3 + 2];
    float d = sqrtf(dx * dx + dy * dy + dz * dz);
    int p = atomicAdd(&woff[c], 1);
    srow[p] = r;
    sdist[p] = d;
}

// ------------- prep: transpose + bf16 all weights (all layers) -------------
__global__ __launch_bounds__(256) void prep_kernel(
    const float* __restrict__ w1, const float* __restrict__ w2,
    const float* __restrict__ u1, const float* __restrict__ u2,
    const float* __restrict__ lin_w,
    short* __restrict__ w1t, short* __restrict__ w2t,
    short* __restrict__ u1t, short* __restrict__ u2t, short* __restrict__ lin_wt) {
    int idx = blockIdx.x * 256 + threadIdx.x;
    if (idx < NLAYERS * FF * FF) {
        int l = idx >> 14, r = idx & 16383, a = r >> 7, b = r & 127;
        size_t src = (size_t)l * FF * FF + (size_t)b * FF + a;  // [l][b][a]
        w2t[idx] = f2bf(w2[src]);
        u1t[idx] = f2bf(u1[src]);
        u2t[idx] = f2bf(u2[src]);
        lin_wt[idx] = f2bf(lin_w[src]);
    }
    if (idx < NLAYERS * FF * 64) {
        int l = idx >> 13, r = idx & 8191, fo = r >> 6, g = r & 63;
        w1t[idx] = f2bf(g < GG ? w1[((size_t)l * GG + g) * FF + fo] : 0.f);
    }
}

// ---------------- vproj0 = v(f32) @ lin_w[0]  via MFMA, bf16 out ----------------
__global__ __launch_bounds__(256) void vproj0_kernel(const float* __restrict__ vb,
                                                     const short* __restrict__ lwt,
                                                     unsigned short* __restrict__ out,
                                                     int N_) {
    const int tid = threadIdx.x;
    const int lane = tid & 63, wave = tid >> 6;
    const int l15 = lane & 15, l4 = lane >> 4;
    const int n0 = wave * 32;
    const int nb0 = blockIdx.x * 64;
    bf16x8 bw[2][4];
#pragma unroll
    for (int n = 0; n < 2; n++)
#pragma unroll
        for (int ks = 0; ks < 4; ks++)
            bw[n][ks] = *(const bf16x8*)&lwt[(n0 + n * 16 + l15) * 128 + ks * 32 + l4 * 8];
#pragma unroll
    for (int m = 0; m < 4; m++) {
        f32x4 acc0 = {0.f, 0.f, 0.f, 0.f}, acc1 = {0.f, 0.f, 0.f, 0.f};
        int arow = nb0 + m * 16 + l15;
        const float* ap = &vb[(size_t)(arow < N_ ? arow : 0) * HH];
#pragma unroll
        for (int ks = 0; ks < 4; ks++) {
            float4 x0 = *(const float4*)&ap[ks * 32 + l4 * 8];
            float4 x1 = *(const float4*)&ap[ks * 32 + l4 * 8 + 4];
            bf16x8 a = {f2bf(x0.x), f2bf(x0.y), f2bf(x0.z), f2bf(x0.w),
                        f2bf(x1.x), f2bf(x1.y), f2bf(x1.z), f2bf(x1.w)};
            acc0 = __builtin_amdgcn_mfma_f32_16x16x32_bf16(a, bw[0][ks], acc0, 0, 0, 0);
            acc1 = __builtin_amdgcn_mfma_f32_16x16x32_bf16(a, bw[1][ks], acc1, 0, 0, 0);
        }
#pragma unroll
        for (int r = 0; r < 4; r++) {
            int gn = nb0 + m * 16 + l4 * 4 + r;
            if (gn < N_) {
                out[(size_t)gn * FF + n0 + l15] = (unsigned short)f2bf(acc0[r]);
                out[(size_t)gn * FF + n0 + 16 + l15] = (unsigned short)f2bf(acc1[r]);
            }
        }
    }
}

// -------- table build: tab[l][i][f] = ((ssp(demb(ih)@w1+b1)@w2)+b2)*C(ih), bf16 ----
__global__ __launch_bounds__(256) void tab_kernel(
    const short* __restrict__ w1t, const float* __restrict__ b1,
    const short* __restrict__ w2t, const float* __restrict__ b2,
    unsigned short* __restrict__ tab) {
    __shared__ __align__(16) short h1_s[64 * 136];
    const int tid = threadIdx.x;
    const int lane = tid & 63, wave = tid >> 6;
    const int l15 = lane & 15, l4 = lane >> 4;
    const int n0w = wave * 32;
    const int l = blockIdx.x / (TAB / 64);
    const int tb0 = (blockIdx.x % (TAB / 64)) * 64;
    const short* w1l = w1t + (size_t)l * FF * 64;
    const short* w2l = w2t + (size_t)l * FF * FF;
    unsigned short* tabl = tab + (size_t)l * TAB * FF;

    bf16x8 bw1[2][2], bw2[2][4];
    float bias1[2], bias2[2];
#pragma unroll
    for (int n = 0; n < 2; n++) {
        const int fo = n0w + n * 16 + l15;
        bias1[n] = b1[(size_t)l * FF + fo];
        bias2[n] = b2[(size_t)l * FF + fo];
#pragma unroll
        for (int ks = 0; ks < 2; ks++)
            bw1[n][ks] = *(const bf16x8*)&w1l[fo * 64 + ks * 32 + l4 * 8];
#pragma unroll
        for (int ks = 0; ks < 4; ks++)
            bw2[n][ks] = *(const bf16x8*)&w2l[fo * 128 + ks * 32 + l4 * 8];
    }

    const float STEP = 5.0f / 49.0f;
    const float COEFF = -0.5f / (STEP * STEP);
#pragma unroll
    for (int m = 0; m < 4; m++) {
        float d = (float)(tb0 + m * 16 + l15) * TABH;
        bf16x8 a0, a1;
#pragma unroll
        for (int j = 0; j < 8; j++) {
            int g0 = l4 * 8 + j;
            float x0 = fmaf((float)g0, -STEP, d);
            a0[j] = f2bf(__expf(COEFF * x0 * x0));
            int g1 = 32 + l4 * 8 + j;
            float x1 = fmaf((float)g1, -STEP, d);
            a1[j] = (g1 < GG) ? f2bf(__expf(COEFF * x1 * x1)) : (short)0;
        }
#pragma unroll
        for (int n = 0; n < 2; n++) {
            f32x4 acc = {bias1[n], bias1[n], bias1[n], bias1[n]};
            acc = __builtin_amdgcn_mfma_f32_16x16x32_bf16(a0, bw1[n][0], acc, 0, 0, 0);
            acc = __builtin_amdgcn_mfma_f32_16x16x32_bf16(a1, bw1[n][1], acc, 0, 0, 0);
            const int f = n0w + n * 16 + l15;
#pragma unroll
            for (int r = 0; r < 4; r++)
                h1_s[(m * 16 + l4 * 4 + r) * 136 + f] = f2bf(ssp(acc[r]));
        }
    }
    __syncthreads();

#pragma unroll
    for (int m = 0; m < 4; m++) {
        f32x4 accA = {bias2[0], bias2[0], bias2[0], bias2[0]};
        f32x4 accB = {bias2[1], bias2[1], bias2[1], bias2[1]};
#pragma unroll
        for (int ks = 0; ks < 4; ks++) {
            bf16x8 a = *(const bf16x8*)&h1_s[(m * 16 + l15) * 136 + ks * 32 + l4 * 8];
            accA = __builtin_amdgcn_mfma_f32_16x16x32_bf16(a, bw2[0][ks], accA, 0, 0, 0);
            accB = __builtin_amdgcn_mfma_f32_16x16x32_bf16(a, bw2[1][ks], accB, 0, 0, 0);
        }
#pragma unroll
        for (int r = 0; r < 4; r++) {
            int entry = tb0 + m * 16 + l4 * 4 + r;
            float de = (float)entry * TABH;
            float C = 0.5f * (cosf(de * 0.6283185307179586f) + 1.0f);
            tabl[(size_t)entry * FF + n0w + l15] = (unsigned short)f2bf(accA[r] * C);
            tabl[(size_t)entry * FF + n0w + 16 + l15] = (unsigned short)f2bf(accB[r] * C);
        }
    }
}

// ===== fused layer: 8-wave blocks; per-wave node-owned CSR agg (table lerp) + MLP =====
// LDS = agg(16.9K) + t1(8.7K); t2 aliases agg. ~25.6 KB. Grid 625 -> 2.44 blk/CU,
// 8 waves/block -> ~19.5 waves/CU (61% occ target).
__global__ __launch_bounds__(512) void layer_kernel(
    const float* __restrict__ sdist, const int* __restrict__ srow,
    const int* __restrict__ off_start, const int* __restrict__ off_end,
    const unsigned short* __restrict__ tab, const unsigned short* __restrict__ vin,
    const short* __restrict__ u1t, const float* __restrict__ ub1,
    const short* __restrict__ u2t, const float* __restrict__ ub2,
    float* __restrict__ vb, const short* __restrict__ lwt_next,
    unsigned short* __restrict__ vout, int N_) {
    __shared__ __align__(16) float agg_s[NPB * 132];
    __shared__ __align__(16) short t1_s[NPB * 136];
    short* t2_s = (short*)agg_s;   // alias: agg dead after MLP GEMM1

    const int tid = threadIdx.x;
    const int lane = tid & 63, wave = tid >> 6;   // 8 waves
    const int l15 = lane & 15, l4 = lane >> 4;
    const int mw = wave >> 2;                     // row half 0..1
    const int n0w = (wave & 3) * 32;              // feature quarter
    const int nb0 = blockIdx.x * NPB;

    // ---- edge aggregation: wave owns nodes [4*wave, 4*wave+4); register acc
    for (int s = 0; s < 4; s++) {
        const int nl = wave * 4 + s;
        const int n = nb0 + nl;
        float acc0 = 0.f, acc1 = 0.f;
        if (n < N_) {
            const int e0 = off_start[n], e1 = off_end[n];
            for (int base = e0; base < e1; base += 64) {
                const int cnt = min(64, e1 - base);
                int eidx = base + lane;
                if (eidx >= e1) eidx = e1 - 1;
                const float md = sdist[eidx];
                const int mr = srow[eidx];
#pragma unroll 4
                for (int i = 0; i < cnt; i++) {
                    const float d = __shfl(md, i);
                    const int r = __shfl(mr, i);
                    float x = d * TABINVH;
                    int ix = (int)x;
                    ix = (ix < TAB - 2) ? ix : (TAB - 2);
                    const float fr = x - (float)ix;
                    const unsigned ta = *(const unsigned*)&tab[(size_t)ix * FF + 2 * lane];
                    const unsigned tb = *(const unsigned*)&tab[(size_t)(ix + 1) * FF + 2 * lane];
                    const unsigned vp = *(const unsigned*)&vin[(size_t)r * FF + 2 * lane];
                    const float w0 = fmaf(fr, bf2f_lo(tb) - bf2f_lo(ta), bf2f_lo(ta));
                    const float w1 = fmaf(fr, bf2f_hi(tb) - bf2f_hi(ta), bf2f_hi(ta));
                    acc0 = fmaf(w0, bf2f_lo(vp), acc0);
                    acc1 = fmaf(w1, bf2f_hi(vp), acc1);
                }
            }
        }
        agg_s[nl * 132 + 2 * lane] = acc0;
        agg_s[nl * 132 + 2 * lane + 1] = acc1;
    }
    __syncthreads();

    // ---- MLP GEMM1: t1 = ssp(agg @ u1 + ub1); wave (mw, n0w) does one 16x32 tile
    {
        bf16x8 bw[2][4];
        float bias[2];
#pragma unroll
        for (int n = 0; n < 2; n++) {
            bias[n] = ub1[n0w + n * 16 + l15];
#pragma unroll
            for (int ks = 0; ks < 4; ks++)
                bw[n][ks] = *(const bf16x8*)&u1t[(n0w + n * 16 + l15) * 128 + ks * 32 + l4 * 8];
        }
        const float* ap = &agg_s[(mw * 16 + l15) * 132];
        f32x4 acc0 = {bias[0], bias[0], bias[0], bias[0]};
        f32x4 acc1 = {bias[1], bias[1], bias[1], bias[1]};
#pragma unroll
        for (int ks = 0; ks < 4; ks++) {
            float4 x0 = *(const float4*)&ap[ks * 32 + l4 * 8];
            float4 x1 = *(const float4*)&ap[ks * 32 + l4 * 8 + 4];
            bf16x8 a = {f2bf(x0.x), f2bf(x0.y), f2bf(x0.z), f2bf(x0.w),
                        f2bf(x1.x), f2bf(x1.y), f2bf(x1.z), f2bf(x1.w)};
            acc0 = __builtin_amdgcn_mfma_f32_16x16x32_bf16(a, bw[0][ks], acc0, 0, 0, 0);
            acc1 = __builtin_amdgcn_mfma_f32_16x16x32_bf16(a, bw[1][ks], acc1, 0, 0, 0);
        }
#pragma unroll
        for (int r = 0; r < 4; r++) {
            int er = mw * 16 + l4 * 4 + r;
            t1_s[er * 136 + n0w + l15] = f2bf(ssp(acc0[r]));
            t1_s[er * 136 + n0w + 16 + l15] = f2bf(ssp(acc1[r]));
        }
    }
    __syncthreads();

    // ---- MLP GEMM2: v_new = v + (t1 @ u2 + ub2); write vb + t2_s (aliases agg)
    {
        bf16x8 bw[2][4];
        float bias[2];
#pragma unroll
        for (int n = 0; n < 2; n++) {
            bias[n] = ub2[n0w + n * 16 + l15];
#pragma unroll
            for (int ks = 0; ks < 4; ks++)
                bw[n][ks] = *(const bf16x8*)&u2t[(n0w + n * 16 + l15) * 128 + ks * 32 + l4 * 8];
        }
        f32x4 acc0 = {bias[0], bias[0], bias[0], bias[0]};
        f32x4 acc1 = {bias[1], bias[1], bias[1], bias[1]};
#pragma unroll
        for (int ks = 0; ks < 4; ks++) {
            bf16x8 a = *(const bf16x8*)&t1_s[(mw * 16 + l15) * 136 + ks * 32 + l4 * 8];
            acc0 = __builtin_amdgcn_mfma_f32_16x16x32_bf16(a, bw[0][ks], acc0, 0, 0, 0);
            acc1 = __builtin_amdgcn_mfma_f32_16x16x32_bf16(a, bw[1][ks], acc1, 0, 0, 0);
        }
        __syncthreads();   // all t1 reads done before t2 (aliases agg... t1 distinct) -- keep order safe
#pragma unroll
        for (int r = 0; r < 4; r++) {
            int er = mw * 16 + l4 * 4 + r;
            int gn = nb0 + er;
            if (gn < N_) {
                size_t i0 = (size_t)gn * HH + n0w + l15;
                size_t i1 = (size_t)gn * HH + n0w + 16 + l15;
                float v0 = vb[i0] + acc0[r];
                float v1 = vb[i1] + acc1[r];
                vb[i0] = v0;
                vb[i1] = v1;
                t2_s[er * 136 + n0w + l15] = f2bf(v0);
                t2_s[er * 136 + n0w + 16 + l15] = f2bf(v1);
            } else {
                t2_s[er * 136 + n0w + l15] = 0;
                t2_s[er * 136 + n0w + 16 + l15] = 0;
            }
        }
    }
    __syncthreads();

    // ---- MLP GEMM3: vout = v_new @ lin_w[l+1] (bf16)
    if (lwt_next) {
        bf16x8 bw[2][4];
#pragma unroll
        for (int n = 0; n < 2; n++)
#pragma unroll
            for (int ks = 0; ks < 4; ks++)
                bw[n][ks] = *(const bf16x8*)&lwt_next[(n0w + n * 16 + l15) * 128 + ks * 32 + l4 * 8];
        f32x4 acc0 = {0.f, 0.f, 0.f, 0.f}, acc1 = {0.f, 0.f, 0.f, 0.f};
#pragma unroll
        for (int ks = 0; ks < 4; ks++) {
            bf16x8 a = *(const bf16x8*)&t2_s[(mw * 16 + l15) * 136 + ks * 32 + l4 * 8];
            acc0 = __builtin_amdgcn_mfma_f32_16x16x32_bf16(a, bw[0][ks], acc0, 0, 0, 0);
            acc1 = __builtin_amdgcn_mfma_f32_16x16x32_bf16(a, bw[1][ks], acc1, 0, 0, 0);
        }
#pragma unroll
        for (int r = 0; r < 4; r++) {
            int gn = nb0 + mw * 16 + l4 * 4 + r;
            if (gn < N_) {
                vout[(size_t)gn * FF + n0w + l15] = (unsigned short)f2bf(acc0[r]);
                vout[(size_t)gn * FF + n0w + 16 + l15] = (unsigned short)f2bf(acc1[r]);
            }
        }
    }
}

extern "C" void kernel_launch(void* const* d_in, const int* in_sizes, int n_in,
                              void* d_out, int out_size, void* d_ws, size_t ws_size,
                              hipStream_t stream) {
    const float* v = (const float*)d_in[0];
    const float* pos = (const float*)d_in[1];
    const float* offs = (const float*)d_in[2];
    const int* edges = (const int*)d_in[3];
    const float* lin_w = (const float*)d_in[4];
    const float* w1 = (const float*)d_in[5];
    const float* b1 = (const float*)d_in[6];
    const float* w2 = (const float*)d_in[7];
    const float* b2 = (const float*)d_in[8];
    const float* u1 = (const float*)d_in[9];
    const float* ub1 = (const float*)d_in[10];
    const float* u2 = (const float*)d_in[11];
    const float* ub2 = (const float*)d_in[12];

    const int N = in_sizes[0] / HH;
    const int E = in_sizes[3] / 2;
    const int* row = edges;
    const int* col = edges + E;

    char* base = (char*)d_ws;
    int* counts = (int*)base;    base += (size_t)N * 4;
    int* woff = (int*)base;      base += (size_t)N * 4;
    int* offsets = (int*)base;   base += (size_t)N * 4;
    int* srow = (int*)base;      base += (size_t)E * 4;
    float* sdist = (float*)base; base += (size_t)E * 4;
    float* vbuf = (float*)base;  base += (size_t)N * HH * 4;
    unsigned short* vprojA = (unsigned short*)base; base += (size_t)N * FF * 2;
    unsigned short* vprojB = (unsigned short*)base; base += (size_t)N * FF * 2;
    short* w1t = (short*)base;   base += (size_t)NLAYERS * FF * 64 * 2;
    short* w2t = (short*)base;   base += (size_t)NLAYERS * FF * FF * 2;
    short* u1t = (short*)base;   base += (size_t)NLAYERS * FF * FF * 2;
    short* u2t = (short*)base;   base += (size_t)NLAYERS * FF * FF * 2;
    short* lin_wt = (short*)base; base += (size_t)NLAYERS * FF * FF * 2;
    unsigned short* tab = (unsigned short*)base;   // 6 * 4096 * 128 bf16 = 6.3 MB

    const int EB = (E + 255) / 256;
    const int NB64 = (N + 63) / 64;
    const int NBn = (N + NPB - 1) / NPB;

    hipMemsetAsync(counts, 0, (size_t)N * 4, stream);
    hist_kernel<<<EB, 256, 0, stream>>>(col, counts, E);
    scan_kernel<<<1, 1024, 0, stream>>>(counts, offsets, woff, N);
    scatter_kernel<<<EB, 256, 0, stream>>>(pos, offs, row, col, woff, srow, sdist, E);
    prep_kernel<<<(NLAYERS * FF * FF + 255) / 256, 256, 0, stream>>>(
        w1, w2, u1, u2, lin_w, w1t, w2t, u1t, u2t, lin_wt);
    tab_kernel<<<NLAYERS * (TAB / 64), 256, 0, stream>>>(w1t, b1, w2t, b2, tab);
    hipMemcpyAsync(vbuf, v, (size_t)N * HH * sizeof(float),
                   hipMemcpyDeviceToDevice, stream);
    vproj0_kernel<<<NB64, 256, 0, stream>>>(v, lin_wt, vprojA, N);

    for (int l = 0; l < NLAYERS; l++) {
        unsigned short* vin = (l & 1) ? vprojB : vprojA;
        unsigned short* vout = (l & 1) ? vprojA : vprojB;
        layer_kernel<<<NBn, 512, 0, stream>>>(
            sdist, srow, offsets, woff, tab + (size_t)l * TAB * FF, vin,
            u1t + (size_t)l * FF * FF, ub1 + (size_t)l * HH,
            u2t + (size_t)l * FF * FF, ub2 + (size_t)l * HH, vbuf,
            (l + 1 < NLAYERS) ? (lin_wt + (size_t)(l + 1) * FF * FF) : nullptr,
            vout, N);
    }
    hipMemcpyAsync(d_out, vbuf, (size_t)N * HH * sizeof(float),
                   hipMemcpyDeviceToDevice, stream);
}

// Round 12
// 424.043 us; speedup vs baseline: 2.4899x; 1.0067x over previous
//
#include <hip/hip_runtime.h>
#include <hip/hip_bf16.h>
#include <math.h>

#define HH 128
#define FF 128
#define GG 50
#define NLAYERS 6
#define NPB 32
#define TAB 4096
#define TABH 0.001953125f   // 8.0 / 4096
#define TABINVH 512.0f

typedef __attribute__((ext_vector_type(8))) short bf16x8;
typedef __attribute__((ext_vector_type(4))) float f32x4;

static __device__ __forceinline__ float ssp(float x) {
    return fmaxf(x, 0.f) + __logf(1.f + __expf(-fabsf(x))) - 0.6931471805599453f;
}

static __device__ __forceinline__ short f2bf(float x) {
    union { float f; unsigned u; } c; c.f = x;
    unsigned r = (c.u + 0x7FFF + ((c.u >> 16) & 1)) >> 16;
    return (short)r;
}

static __device__ __forceinline__ float bf2f_lo(unsigned p) {
    union { unsigned u; float f; } c; c.u = p << 16; return c.f;
}
static __device__ __forceinline__ float bf2f_hi(unsigned p) {
    union { unsigned u; float f; } c; c.u = p & 0xFFFF0000u; return c.f;
}

// ---------------- sort pipeline: hist -> scan -> scatter ----------------
__global__ void hist_kernel(const int* __restrict__ col, int* __restrict__ counts, int E_) {
    int e = blockIdx.x * 256 + threadIdx.x;
    if (e < E_) atomicAdd(&counts[col[e]], 1);
}

__global__ __launch_bounds__(1024) void scan_kernel(const int* __restrict__ counts,
                                                    int* __restrict__ offsets,
                                                    int* __restrict__ woff, int N_) {
    __shared__ int wsum[16];
    __shared__ int carry_s;
    const int tid = threadIdx.x;
    const int lane = tid & 63, wid = tid >> 6;
    if (tid == 0) carry_s = 0;
    __syncthreads();
    for (int base = 0; base < N_; base += 1024) {
        int i = base + tid;
        int val = (i < N_) ? counts[i] : 0;
        int x = val;
#pragma unroll
        for (int d = 1; d < 64; d <<= 1) {
            int t = __shfl_up(x, d, 64);
            if (lane >= d) x += t;
        }
        if (lane == 63) wsum[wid] = x;
        int carry = carry_s;
        __syncthreads();
        if (wid == 0) {
            int s = (lane < 16) ? wsum[lane] : 0;
#pragma unroll
            for (int d = 1; d < 16; d <<= 1) {
                int t = __shfl_up(s, d, 64);
                if (lane >= d) s += t;
            }
            if (lane < 16) wsum[lane] = s;
            if (lane == 15) carry_s = carry + s;
        }
        __syncthreads();
        int woffset = (wid > 0) ? wsum[wid - 1] : 0;
        if (i < N_) {
            int ex = carry + woffset + x - val;  // exclusive
            offsets[i] = ex;
            woff[i] = ex;
        }
        __syncthreads();
    }
}

__global__ void scatter_kernel(const float* __restrict__ pos,
                               const float* __restrict__ offs,
                               const int* __restrict__ row,
                               const int* __restrict__ col,
                               int* __restrict__ woff,
                               int* __restrict__ srow,
                               float* __restrict__ sdist, int E_) {
    int e = blockIdx.x * 256 + threadIdx.x;
    if (e >= E_) return;
    int r = row[e], c = col[e];
    float dx = pos[c * 3 + 0] + offs[e * 3 + 0] - pos[r * 3 + 0];
    float dy = pos[c * 3 + 1] + offs[e * 3 + 1] - pos[r * 3 + 1];
    float dz = pos[c * 3 + 2] + offs[e * 3 + 2] - pos[r * 3 + 2];
    float d = sqrtf(dx * dx + dy * dy + dz * dz);
    int p = atomicAdd(&woff[c], 1);
    srow[p] = r;
    sdist[p] = d;
}

// ------------- prep: transpose + bf16 all weights (all layers) -------------
__global__ __launch_bounds__(256) void prep_kernel(
    const float* __restrict__ w1, const float* __restrict__ w2,
    const float* __restrict__ u1, const float* __restrict__ u2,
    const float* __restrict__ lin_w,
    short* __restrict__ w1t, short* __restrict__ w2t,
    short* __restrict__ u1t, short* __restrict__ u2t, short* __restrict__ lin_wt) {
    int idx = blockIdx.x * 256 + threadIdx.x;
    if (idx < NLAYERS * FF * FF) {
        int l = idx >> 14, r = idx & 16383, a = r >> 7, b = r & 127;
        size_t src = (size_t)l * FF * FF + (size_t)b * FF + a;  // [l][b][a]
        w2t[idx] = f2bf(w2[src]);
        u1t[idx] = f2bf(u1[src]);
        u2t[idx] = f2bf(u2[src]);
        lin_wt[idx] = f2bf(lin_w[src]);
    }
    if (idx < NLAYERS * FF * 64) {
        int l = idx >> 13, r = idx & 8191, fo = r >> 6, g = r & 63;
        w1t[idx] = f2bf(g < GG ? w1[((size_t)l * GG + g) * FF + fo] : 0.f);
    }
}

// ---------------- vproj0 = v(f32) @ lin_w[0]  via MFMA, bf16 out ----------------
__global__ __launch_bounds__(256) void vproj0_kernel(const float* __restrict__ vb,
                                                     const short* __restrict__ lwt,
                                                     unsigned short* __restrict__ out,
                                                     int N_) {
    const int tid = threadIdx.x;
    const int lane = tid & 63, wave = tid >> 6;
    const int l15 = lane & 15, l4 = lane >> 4;
    const int n0 = wave * 32;
    const int nb0 = blockIdx.x * 64;
    bf16x8 bw[2][4];
#pragma unroll
    for (int n = 0; n < 2; n++)
#pragma unroll
        for (int ks = 0; ks < 4; ks++)
            bw[n][ks] = *(const bf16x8*)&lwt[(n0 + n * 16 + l15) * 128 + ks * 32 + l4 * 8];
#pragma unroll
    for (int m = 0; m < 4; m++) {
        f32x4 acc0 = {0.f, 0.f, 0.f, 0.f}, acc1 = {0.f, 0.f, 0.f, 0.f};
        int arow = nb0 + m * 16 + l15;
        const float* ap = &vb[(size_t)(arow < N_ ? arow : 0) * HH];
#pragma unroll
        for (int ks = 0; ks < 4; ks++) {
            float4 x0 = *(const float4*)&ap[ks * 32 + l4 * 8];
            float4 x1 = *(const float4*)&ap[ks * 32 + l4 * 8 + 4];
            bf16x8 a = {f2bf(x0.x), f2bf(x0.y), f2bf(x0.z), f2bf(x0.w),
                        f2bf(x1.x), f2bf(x1.y), f2bf(x1.z), f2bf(x1.w)};
            acc0 = __builtin_amdgcn_mfma_f32_16x16x32_bf16(a, bw[0][ks], acc0, 0, 0, 0);
            acc1 = __builtin_amdgcn_mfma_f32_16x16x32_bf16(a, bw[1][ks], acc1, 0, 0, 0);
        }
#pragma unroll
        for (int r = 0; r < 4; r++) {
            int gn = nb0 + m * 16 + l4 * 4 + r;
            if (gn < N_) {
                out[(size_t)gn * FF + n0 + l15] = (unsigned short)f2bf(acc0[r]);
                out[(size_t)gn * FF + n0 + 16 + l15] = (unsigned short)f2bf(acc1[r]);
            }
        }
    }
}

// -------- table build: tab[l][i][f] = ((ssp(demb(ih)@w1+b1)@w2)+b2)*C(ih), bf16 ----
__global__ __launch_bounds__(256) void tab_kernel(
    const short* __restrict__ w1t, const float* __restrict__ b1,
    const short* __restrict__ w2t, const float* __restrict__ b2,
    unsigned short* __restrict__ tab) {
    __shared__ __align__(16) short h1_s[64 * 136];
    const int tid = threadIdx.x;
    const int lane = tid & 63, wave = tid >> 6;
    const int l15 = lane & 15, l4 = lane >> 4;
    const int n0w = wave * 32;
    const int l = blockIdx.x / (TAB / 64);
    const int tb0 = (blockIdx.x % (TAB / 64)) * 64;
    const short* w1l = w1t + (size_t)l * FF * 64;
    const short* w2l = w2t + (size_t)l * FF * FF;
    unsigned short* tabl = tab + (size_t)l * TAB * FF;

    bf16x8 bw1[2][2], bw2[2][4];
    float bias1[2], bias2[2];
#pragma unroll
    for (int n = 0; n < 2; n++) {
        const int fo = n0w + n * 16 + l15;
        bias1[n] = b1[(size_t)l * FF + fo];
        bias2[n] = b2[(size_t)l * FF + fo];
#pragma unroll
        for (int ks = 0; ks < 2; ks++)
            bw1[n][ks] = *(const bf16x8*)&w1l[fo * 64 + ks * 32 + l4 * 8];
#pragma unroll
        for (int ks = 0; ks < 4; ks++)
            bw2[n][ks] = *(const bf16x8*)&w2l[fo * 128 + ks * 32 + l4 * 8];
    }

    const float STEP = 5.0f / 49.0f;
    const float COEFF = -0.5f / (STEP * STEP);
#pragma unroll
    for (int m = 0; m < 4; m++) {
        float d = (float)(tb0 + m * 16 + l15) * TABH;
        bf16x8 a0, a1;
#pragma unroll
        for (int j = 0; j < 8; j++) {
            int g0 = l4 * 8 + j;
            float x0 = fmaf((float)g0, -STEP, d);
            a0[j] = f2bf(__expf(COEFF * x0 * x0));
            int g1 = 32 + l4 * 8 + j;
            float x1 = fmaf((float)g1, -STEP, d);
            a1[j] = (g1 < GG) ? f2bf(__expf(COEFF * x1 * x1)) : (short)0;
        }
#pragma unroll
        for (int n = 0; n < 2; n++) {
            f32x4 acc = {bias1[n], bias1[n], bias1[n], bias1[n]};
            acc = __builtin_amdgcn_mfma_f32_16x16x32_bf16(a0, bw1[n][0], acc, 0, 0, 0);
            acc = __builtin_amdgcn_mfma_f32_16x16x32_bf16(a1, bw1[n][1], acc, 0, 0, 0);
            const int f = n0w + n * 16 + l15;
#pragma unroll
            for (int r = 0; r < 4; r++)
                h1_s[(m * 16 + l4 * 4 + r) * 136 + f] = f2bf(ssp(acc[r]));
        }
    }
    __syncthreads();

#pragma unroll
    for (int m = 0; m < 4; m++) {
        f32x4 accA = {bias2[0], bias2[0], bias2[0], bias2[0]};
        f32x4 accB = {bias2[1], bias2[1], bias2[1], bias2[1]};
#pragma unroll
        for (int ks = 0; ks < 4; ks++) {
            bf16x8 a = *(const bf16x8*)&h1_s[(m * 16 + l15) * 136 + ks * 32 + l4 * 8];
            accA = __builtin_amdgcn_mfma_f32_16x16x32_bf16(a, bw2[0][ks], accA, 0, 0, 0);
            accB = __builtin_amdgcn_mfma_f32_16x16x32_bf16(a, bw2[1][ks], accB, 0, 0, 0);
        }
#pragma unroll
        for (int r = 0; r < 4; r++) {
            int entry = tb0 + m * 16 + l4 * 4 + r;
            float de = (float)entry * TABH;
            float C = 0.5f * (cosf(de * 0.6283185307179586f) + 1.0f);
            tabl[(size_t)entry * FF + n0w + l15] = (unsigned short)f2bf(accA[r] * C);
            tabl[(size_t)entry * FF + n0w + 16 + l15] = (unsigned short)f2bf(accB[r] * C);
        }
    }
}

// ===== fused layer: 16-wave blocks (1024 thr); wave owns 2 nodes; MLP 16x16 tiles =====
// LDS = agg(16.9K) + t1(8.7K); t2 aliases agg. 2 blk/CU x 16 waves = 32 waves/CU cap.
__global__ __launch_bounds__(1024) void layer_kernel(
    const float* __restrict__ sdist, const int* __restrict__ srow,
    const int* __restrict__ off_start, const int* __restrict__ off_end,
    const unsigned short* __restrict__ tab, const unsigned short* __restrict__ vin,
    const short* __restrict__ u1t, const float* __restrict__ ub1,
    const short* __restrict__ u2t, const float* __restrict__ ub2,
    float* __restrict__ vb, const short* __restrict__ lwt_next,
    unsigned short* __restrict__ vout, int N_) {
    __shared__ __align__(16) float agg_s[NPB * 132];
    __shared__ __align__(16) short t1_s[NPB * 136];
    short* t2_s = (short*)agg_s;   // alias: agg dead after MLP GEMM1

    const int tid = threadIdx.x;
    const int lane = tid & 63, wave = tid >> 6;   // 16 waves
    const int l15 = lane & 15, l4 = lane >> 4;
    const int mw = wave & 1;                      // row half 0..1
    const int n0c = (wave >> 1) * 16;             // 16-wide feature column group
    const int nb0 = blockIdx.x * NPB;

    // ---- edge aggregation: wave owns nodes [2*wave, 2*wave+2); register acc
    for (int s = 0; s < 2; s++) {
        const int nl = wave * 2 + s;
        const int n = nb0 + nl;
        float acc0 = 0.f, acc1 = 0.f;
        if (n < N_) {
            const int e0 = off_start[n], e1 = off_end[n];
            for (int base = e0; base < e1; base += 64) {
                const int cnt = min(64, e1 - base);
                int eidx = base + lane;
                if (eidx >= e1) eidx = e1 - 1;
                const float md = sdist[eidx];
                const int mr = srow[eidx];
#pragma unroll 4
                for (int i = 0; i < cnt; i++) {
                    const float d = __shfl(md, i);
                    const int r = __shfl(mr, i);
                    float x = d * TABINVH;
                    int ix = (int)x;
                    ix = (ix < TAB - 2) ? ix : (TAB - 2);
                    const float fr = x - (float)ix;
                    const unsigned ta = *(const unsigned*)&tab[(size_t)ix * FF + 2 * lane];
                    const unsigned tb = *(const unsigned*)&tab[(size_t)(ix + 1) * FF + 2 * lane];
                    const unsigned vp = *(const unsigned*)&vin[(size_t)r * FF + 2 * lane];
                    const float w0 = fmaf(fr, bf2f_lo(tb) - bf2f_lo(ta), bf2f_lo(ta));
                    const float w1 = fmaf(fr, bf2f_hi(tb) - bf2f_hi(ta), bf2f_hi(ta));
                    acc0 = fmaf(w0, bf2f_lo(vp), acc0);
                    acc1 = fmaf(w1, bf2f_hi(vp), acc1);
                }
            }
        }
        agg_s[nl * 132 + 2 * lane] = acc0;
        agg_s[nl * 132 + 2 * lane + 1] = acc1;
    }
    __syncthreads();

    // ---- MLP GEMM1: t1 = ssp(agg @ u1 + ub1); wave does 16x16 tile (mw, n0c)
    {
        bf16x8 bw[4];
        const float bias = ub1[n0c + l15];
#pragma unroll
        for (int ks = 0; ks < 4; ks++)
            bw[ks] = *(const bf16x8*)&u1t[(n0c + l15) * 128 + ks * 32 + l4 * 8];
        const float* ap = &agg_s[(mw * 16 + l15) * 132];
        f32x4 acc = {bias, bias, bias, bias};
#pragma unroll
        for (int ks = 0; ks < 4; ks++) {
            float4 x0 = *(const float4*)&ap[ks * 32 + l4 * 8];
            float4 x1 = *(const float4*)&ap[ks * 32 + l4 * 8 + 4];
            bf16x8 a = {f2bf(x0.x), f2bf(x0.y), f2bf(x0.z), f2bf(x0.w),
                        f2bf(x1.x), f2bf(x1.y), f2bf(x1.z), f2bf(x1.w)};
            acc = __builtin_amdgcn_mfma_f32_16x16x32_bf16(a, bw[ks], acc, 0, 0, 0);
        }
#pragma unroll
        for (int r = 0; r < 4; r++) {
            int er = mw * 16 + l4 * 4 + r;
            t1_s[er * 136 + n0c + l15] = f2bf(ssp(acc[r]));
        }
    }
    __syncthreads();

    // ---- MLP GEMM2: v_new = v + (t1 @ u2 + ub2); write vb + t2_s (aliases agg)
    {
        bf16x8 bw[4];
        const float bias = ub2[n0c + l15];
#pragma unroll
        for (int ks = 0; ks < 4; ks++)
            bw[ks] = *(const bf16x8*)&u2t[(n0c + l15) * 128 + ks * 32 + l4 * 8];
        f32x4 acc = {bias, bias, bias, bias};
#pragma unroll
        for (int ks = 0; ks < 4; ks++) {
            bf16x8 a = *(const bf16x8*)&t1_s[(mw * 16 + l15) * 136 + ks * 32 + l4 * 8];
            acc = __builtin_amdgcn_mfma_f32_16x16x32_bf16(a, bw[ks], acc, 0, 0, 0);
        }
        __syncthreads();   // all t1 reads done before t2 overwrite of agg pool
#pragma unroll
        for (int r = 0; r < 4; r++) {
            int er = mw * 16 + l4 * 4 + r;
            int gn = nb0 + er;
            if (gn < N_) {
                size_t i0 = (size_t)gn * HH + n0c + l15;
                float v0 = vb[i0] + acc[r];
                vb[i0] = v0;
                t2_s[er * 136 + n0c + l15] = f2bf(v0);
            } else {
                t2_s[er * 136 + n0c + l15] = 0;
            }
        }
    }
    __syncthreads();

    // ---- MLP GEMM3: vout = v_new @ lin_w[l+1] (bf16)
    if (lwt_next) {
        bf16x8 bw[4];
#pragma unroll
        for (int ks = 0; ks < 4; ks++)
            bw[ks] = *(const bf16x8*)&lwt_next[(n0c + l15) * 128 + ks * 32 + l4 * 8];
        f32x4 acc = {0.f, 0.f, 0.f, 0.f};
#pragma unroll
        for (int ks = 0; ks < 4; ks++) {
            bf16x8 a = *(const bf16x8*)&t2_s[(mw * 16 + l15) * 136 + ks * 32 + l4 * 8];
            acc = __builtin_amdgcn_mfma_f32_16x16x32_bf16(a, bw[ks], acc, 0, 0, 0);
        }
#pragma unroll
        for (int r = 0; r < 4; r++) {
            int gn = nb0 + mw * 16 + l4 * 4 + r;
            if (gn < N_) {
                vout[(size_t)gn * FF + n0c + l15] = (unsigned short)f2bf(acc[r]);
            }
        }
    }
}

extern "C" void kernel_launch(void* const* d_in, const int* in_sizes, int n_in,
                              void* d_out, int out_size, void* d_ws, size_t ws_size,
                              hipStream_t stream) {
    const float* v = (const float*)d_in[0];
    const float* pos = (const float*)d_in[1];
    const float* offs = (const float*)d_in[2];
    const int* edges = (const int*)d_in[3];
    const float* lin_w = (const float*)d_in[4];
    const float* w1 = (const float*)d_in[5];
    const float* b1 = (const float*)d_in[6];
    const float* w2 = (const float*)d_in[7];
    const float* b2 = (const float*)d_in[8];
    const float* u1 = (const float*)d_in[9];
    const float* ub1 = (const float*)d_in[10];
    const float* u2 = (const float*)d_in[11];
    const float* ub2 = (const float*)d_in[12];

    const int N = in_sizes[0] / HH;
    const int E = in_sizes[3] / 2;
    const int* row = edges;
    const int* col = edges + E;

    char* base = (char*)d_ws;
    int* counts = (int*)base;    base += (size_t)N * 4;
    int* woff = (int*)base;      base += (size_t)N * 4;
    int* offsets = (int*)base;   base += (size_t)N * 4;
    int* srow = (int*)base;      base += (size_t)E * 4;
    float* sdist = (float*)base; base += (size_t)E * 4;
    unsigned short* vprojA = (unsigned short*)base; base += (size_t)N * FF * 2;
    unsigned short* vprojB = (unsigned short*)base; base += (size_t)N * FF * 2;
    short* w1t = (short*)base;   base += (size_t)NLAYERS * FF * 64 * 2;
    short* w2t = (short*)base;   base += (size_t)NLAYERS * FF * FF * 2;
    short* u1t = (short*)base;   base += (size_t)NLAYERS * FF * FF * 2;
    short* u2t = (short*)base;   base += (size_t)NLAYERS * FF * FF * 2;
    short* lin_wt = (short*)base; base += (size_t)NLAYERS * FF * FF * 2;
    unsigned short* tab = (unsigned short*)base;   // 6 * 4096 * 128 bf16 = 6.3 MB

    float* vbuf = (float*)d_out;   // residual state lives in d_out (final copy elided)

    const int EB = (E + 255) / 256;
    const int NB64 = (N + 63) / 64;
    const int NBn = (N + NPB - 1) / NPB;

    hipMemsetAsync(counts, 0, (size_t)N * 4, stream);
    hist_kernel<<<EB, 256, 0, stream>>>(col, counts, E);
    scan_kernel<<<1, 1024, 0, stream>>>(counts, offsets, woff, N);
    scatter_kernel<<<EB, 256, 0, stream>>>(pos, offs, row, col, woff, srow, sdist, E);
    prep_kernel<<<(NLAYERS * FF * FF + 255) / 256, 256, 0, stream>>>(
        w1, w2, u1, u2, lin_w, w1t, w2t, u1t, u2t, lin_wt);
    tab_kernel<<<NLAYERS * (TAB / 64), 256, 0, stream>>>(w1t, b1, w2t, b2, tab);
    hipMemcpyAsync(vbuf, v, (size_t)N * HH * sizeof(float),
                   hipMemcpyDeviceToDevice, stream);
    vproj0_kernel<<<NB64, 256, 0, stream>>>(v, lin_wt, vprojA, N);

    for (int l = 0; l < NLAYERS; l++) {
        unsigned short* vin = (l & 1) ? vprojB : vprojA;
        unsigned short* vout = (l & 1) ? vprojA : vprojB;
        layer_kernel<<<NBn, 1024, 0, stream>>>(
            sdist, srow, offsets, woff, tab + (size_t)l * TAB * FF, vin,
            u1t + (size_t)l * FF * FF, ub1 + (size_t)l * HH,
            u2t + (size_t)l * FF * FF, ub2 + (size_t)l * HH, vbuf,
            (l + 1 < NLAYERS) ? (lin_wt + (size_t)(l + 1) * FF * FF) : nullptr,
            vout, N);
    }
}